// Round 11
// baseline (422.435 us; speedup 1.0000x reference)
//
#include <hip/hip_runtime.h>

#define N_NODES  50000
#define N_EDGES  640000
#define N_GRAPHS 500
static constexpr float BN_EPS = 1e-5f;
#define SCAN_NB ((N_NODES + 255) / 256)   // 196 blocks

// ---------------------------------------------------------------------------
__global__ void k_degcnt(const int* __restrict__ dst, const float* __restrict__ w,
                         float* __restrict__ wdeg, int* __restrict__ cnt, int E) {
    int i = blockIdx.x * blockDim.x + threadIdx.x;
    if (i < E) {
        int d = dst[i];
        atomicAdd(&wdeg[d], w[i]);
        atomicAdd(&cnt[d], 1);
    }
}

__global__ void k_dinv(float* __restrict__ wdeg, int n) {
    int i = blockIdx.x * blockDim.x + threadIdx.x;
    if (i < n) wdeg[i] = rsqrtf(wdeg[i] + 1.0f);
}

// --- 3-phase hierarchical exclusive scan of cnt[N] -> offs[N+1] (+cursor) ---
__global__ void k_scan1(const int* __restrict__ cnt, int* __restrict__ bsum, int n) {
    __shared__ int red[256];
    int i = blockIdx.x * 256 + threadIdx.x;
    red[threadIdx.x] = (i < n) ? cnt[i] : 0;
    __syncthreads();
    for (int off = 128; off > 0; off >>= 1) {
        if (threadIdx.x < off) red[threadIdx.x] += red[threadIdx.x + off];
        __syncthreads();
    }
    if (threadIdx.x == 0) bsum[blockIdx.x] = red[0];
}

__global__ void k_scan2(const int* __restrict__ bsum, int* __restrict__ bpre, int nb) {
    __shared__ int part[256];
    int t = threadIdx.x;
    part[t] = (t < nb) ? bsum[t] : 0;
    __syncthreads();
    for (int off = 1; off < 256; off <<= 1) {
        int v = (t >= off) ? part[t - off] : 0;
        __syncthreads();
        part[t] += v;
        __syncthreads();
    }
    if (t < nb) bpre[t] = (t == 0) ? 0 : part[t - 1];
}

__global__ void k_scan3(const int* __restrict__ cnt, const int* __restrict__ bpre,
                        int* __restrict__ offs, int* __restrict__ cursor, int n) {
    __shared__ int part[256];
    int i = blockIdx.x * 256 + threadIdx.x;
    int t = threadIdx.x;
    int v = (i < n) ? cnt[i] : 0;
    part[t] = v;
    __syncthreads();
    for (int off = 1; off < 256; off <<= 1) {
        int u = (t >= off) ? part[t - off] : 0;
        __syncthreads();
        part[t] += u;
        __syncthreads();
    }
    int excl = bpre[blockIdx.x] + part[t] - v;
    if (i < n) {
        offs[i] = excl;
        cursor[i] = excl;
    }
    if (i == n - 1) offs[n] = N_EDGES;
}

__global__ void k_fill(const int* __restrict__ src, const int* __restrict__ dst,
                       const float* __restrict__ w, const float* __restrict__ dinv,
                       int* __restrict__ cursor, int2* __restrict__ csr, int E) {
    int e = blockIdx.x * blockDim.x + threadIdx.x;
    if (e < E) {
        int s = src[e], d = dst[e];
        int pos = atomicAdd(&cursor[d], 1);
        csr[pos] = make_int2(s, __float_as_int(dinv[s] * w[e] * dinv[d]));
    }
}

// Fold bias+BN into per-channel affine. Layer1 additionally folds W1 (rank-1).
__global__ void k_bnprep_all(
    const float* W1,
    const float* b1, const float* g1, const float* be1, const float* m1, const float* v1,
    const float* b2, const float* g2, const float* be2, const float* m2, const float* v2,
    const float* b3, const float* g3, const float* be3, const float* m3, const float* v3,
    float* kA1, float* kB1, float* kA2, float* kB2, float* kA3, float* kB3) {
    int t = threadIdx.x;
    if (t < 64) {
        float s = g1[t] * rsqrtf(v1[t] + BN_EPS);
        kA1[t] = W1[t] * s;
        kB1[t] = (b1[t] - m1[t]) * s + be1[t];
    } else if (t < 192) {
        int c = t - 64;
        float s = g2[c] * rsqrtf(v2[c] + BN_EPS);
        kA2[c] = s; kB2[c] = (b2[c] - m2[c]) * s + be2[c];
    } else if (t < 320) {
        int c = t - 192;
        float s = g3[c] * rsqrtf(v3[c] + BN_EPS);
        kA3[c] = s; kB3[c] = (b3[c] - m3[c]) * s + be3[c];
    }
}

// Layer-1 scalar aggregation over the 200KB x table.
__global__ void k_aggx(const int* __restrict__ offs, const int2* __restrict__ csr,
                       const float* __restrict__ x, const float* __restrict__ dinv,
                       float* __restrict__ aggx, int n) {
    int i = blockIdx.x * blockDim.x + threadIdx.x;
    if (i >= n) return;
    float acc = 0.f;
    int e0 = offs[i], e1 = offs[i + 1];
    for (int j = e0; j < e1; ++j) {
        int2 e = csr[j];
        acc += x[e.x] * __int_as_float(e.y);
    }
    float di = dinv[i];
    aggx[i] = acc + x[i] * di * di;
}

// ---------------------------------------------------------------------------
// Fused layer-1-matmul + layer-2 aggregation. 4 threads/node, 16 ch each:
// csr+aggx loaded 4x per edge (was 16x) -> 8 VMEM/edge vs 32 (r10: VMEM-issue
// bound gathers).
__global__ void k_gather2F(const int* __restrict__ offs, const int2* __restrict__ csr,
                           const float* __restrict__ aggx, const float* __restrict__ dinv,
                           const float* __restrict__ kA1, const float* __restrict__ kB1,
                           float* __restrict__ agg2, int n) {
    int gid = blockIdx.x * blockDim.x + threadIdx.x;
    int node = gid >> 2;
    if (node >= n) return;
    int c16 = (gid & 3) * 16;
    float4 wa0 = *(const float4*)(kA1 + c16 + 0);
    float4 wa1 = *(const float4*)(kA1 + c16 + 4);
    float4 wa2 = *(const float4*)(kA1 + c16 + 8);
    float4 wa3 = *(const float4*)(kA1 + c16 + 12);
    float4 wb0 = *(const float4*)(kB1 + c16 + 0);
    float4 wb1 = *(const float4*)(kB1 + c16 + 4);
    float4 wb2 = *(const float4*)(kB1 + c16 + 8);
    float4 wb3 = *(const float4*)(kB1 + c16 + 12);
    float4 a0 = {0.f,0.f,0.f,0.f}, a1 = a0, a2 = a0, a3 = a0;
    int e0 = offs[node], e1 = offs[node + 1];
    for (int j = e0; j < e1; ++j) {
        int2 e = csr[j];
        float a = aggx[e.x];
        float nm = __int_as_float(e.y);
        a0.x += nm * fmaxf(a * wa0.x + wb0.x, 0.f);
        a0.y += nm * fmaxf(a * wa0.y + wb0.y, 0.f);
        a0.z += nm * fmaxf(a * wa0.z + wb0.z, 0.f);
        a0.w += nm * fmaxf(a * wa0.w + wb0.w, 0.f);
        a1.x += nm * fmaxf(a * wa1.x + wb1.x, 0.f);
        a1.y += nm * fmaxf(a * wa1.y + wb1.y, 0.f);
        a1.z += nm * fmaxf(a * wa1.z + wb1.z, 0.f);
        a1.w += nm * fmaxf(a * wa1.w + wb1.w, 0.f);
        a2.x += nm * fmaxf(a * wa2.x + wb2.x, 0.f);
        a2.y += nm * fmaxf(a * wa2.y + wb2.y, 0.f);
        a2.z += nm * fmaxf(a * wa2.z + wb2.z, 0.f);
        a2.w += nm * fmaxf(a * wa2.w + wb2.w, 0.f);
        a3.x += nm * fmaxf(a * wa3.x + wb3.x, 0.f);
        a3.y += nm * fmaxf(a * wa3.y + wb3.y, 0.f);
        a3.z += nm * fmaxf(a * wa3.z + wb3.z, 0.f);
        a3.w += nm * fmaxf(a * wa3.w + wb3.w, 0.f);
    }
    float di = dinv[node];
    float d2 = di * di;
    float a = aggx[node];
    a0.x += d2 * fmaxf(a * wa0.x + wb0.x, 0.f);
    a0.y += d2 * fmaxf(a * wa0.y + wb0.y, 0.f);
    a0.z += d2 * fmaxf(a * wa0.z + wb0.z, 0.f);
    a0.w += d2 * fmaxf(a * wa0.w + wb0.w, 0.f);
    a1.x += d2 * fmaxf(a * wa1.x + wb1.x, 0.f);
    a1.y += d2 * fmaxf(a * wa1.y + wb1.y, 0.f);
    a1.z += d2 * fmaxf(a * wa1.z + wb1.z, 0.f);
    a1.w += d2 * fmaxf(a * wa1.w + wb1.w, 0.f);
    a2.x += d2 * fmaxf(a * wa2.x + wb2.x, 0.f);
    a2.y += d2 * fmaxf(a * wa2.y + wb2.y, 0.f);
    a2.z += d2 * fmaxf(a * wa2.z + wb2.z, 0.f);
    a2.w += d2 * fmaxf(a * wa2.w + wb2.w, 0.f);
    a3.x += d2 * fmaxf(a * wa3.x + wb3.x, 0.f);
    a3.y += d2 * fmaxf(a * wa3.y + wb3.y, 0.f);
    a3.z += d2 * fmaxf(a * wa3.z + wb3.z, 0.f);
    a3.w += d2 * fmaxf(a * wa3.w + wb3.w, 0.f);
    float* o = agg2 + (size_t)node * 64 + c16;
    *(float4*)(o + 0) = a0;
    *(float4*)(o + 4) = a1;
    *(float4*)(o + 8) = a2;
    *(float4*)(o + 12) = a3;
}

// ---------------------------------------------------------------------------
// Channel-sliced gather (layer 3): slice = blockIdx%8 -> XCD-local 3.2MB table.
// 1 thread per node per slice (16 ch): csr loaded once per edge, 4 independent
// float4 gathers -> 5 VMEM/edge-slice vs 8 (r10: VMEM-issue bound).
__global__ void k_gatherS16(const int* __restrict__ offs, const int2* __restrict__ csr,
                            const float* __restrict__ Hs, const float* __restrict__ dinv,
                            float* __restrict__ aggs, int n) {
    int slice = blockIdx.x & 7;
    int node = (blockIdx.x >> 3) * 256 + threadIdx.x;
    if (node >= n) return;
    const float* Hb = Hs + (size_t)slice * ((size_t)n * 16);
    float4 a0 = {0.f,0.f,0.f,0.f}, a1 = a0, a2 = a0, a3 = a0;
    int e0 = offs[node], e1 = offs[node + 1];
    for (int j = e0; j < e1; ++j) {
        int2 e = csr[j];
        float nm = __int_as_float(e.y);
        const float4* h = (const float4*)(Hb + (size_t)e.x * 16);
        float4 h0 = h[0], h1 = h[1], h2 = h[2], h3 = h[3];
        a0.x += h0.x * nm; a0.y += h0.y * nm; a0.z += h0.z * nm; a0.w += h0.w * nm;
        a1.x += h1.x * nm; a1.y += h1.y * nm; a1.z += h1.z * nm; a1.w += h1.w * nm;
        a2.x += h2.x * nm; a2.y += h2.y * nm; a2.z += h2.z * nm; a2.w += h2.w * nm;
        a3.x += h3.x * nm; a3.y += h3.y * nm; a3.z += h3.z * nm; a3.w += h3.w * nm;
    }
    float di = dinv[node];
    float d2 = di * di;
    const float4* h = (const float4*)(Hb + (size_t)node * 16);
    float4 h0 = h[0], h1 = h[1], h2 = h[2], h3 = h[3];
    a0.x += h0.x * d2; a0.y += h0.y * d2; a0.z += h0.z * d2; a0.w += h0.w * d2;
    a1.x += h1.x * d2; a1.y += h1.y * d2; a1.z += h1.z * d2; a1.w += h1.w * d2;
    a2.x += h2.x * d2; a2.y += h2.y * d2; a2.z += h2.z * d2; a2.w += h2.w * d2;
    a3.x += h3.x * d2; a3.y += h3.y * d2; a3.z += h3.z * d2; a3.w += h3.w * d2;
    float* o = aggs + (size_t)slice * ((size_t)n * 16) + (size_t)node * 16;
    *(float4*)(o + 0) = a0;
    *(float4*)(o + 4) = a1;
    *(float4*)(o + 8) = a2;
    *(float4*)(o + 12) = a3;
}

// ---------------------------------------------------------------------------
// Register-tiled matmul: 32 nodes/block, x-tile AND W staged in LDS.
// k4/p loops pinned rolled (#pragma unroll 1) — r6/r8 spilled at 256 VGPR when
// the compiler unrolled a load loop. RES=true adds residual and writes
// IN-PLACE (outs may alias res — each slot owned by exactly one thread).
template <int K, int S, bool RES>
__global__ __launch_bounds__(256) void k_mmT(
    const float* __restrict__ Xs, const float* __restrict__ W,
    const float* __restrict__ kA, const float* __restrict__ kB,
    const float* __restrict__ res, float* __restrict__ outs, int n) {
    constexpr int CS = K / S;
    constexpr int KP = K + 4;            // padded LDS row stride (floats)
    constexpr int KH = 64;               // W half-pass rows
    constexpr int NPASS = K / KH;
    __shared__ float xl[32 * KP];
    __shared__ float wl[KH * 128];       // 32 KB
    int base = blockIdx.x * 32;
    int tid = threadIdx.x;
    constexpr int TOT4 = 32 * K / 4;
    constexpr int SL4 = 32 * CS / 4;
    for (int i = tid; i < TOT4; i += 256) {
        int slice = i / SL4;
        int rem = i - slice * SL4;
        int nl = rem / (CS / 4);
        int off4 = (rem % (CS / 4)) * 4;
        int node = base + nl;
        float4 v = {0.f, 0.f, 0.f, 0.f};
        if (node < n)
            v = *(const float4*)(Xs + (size_t)slice * ((size_t)n * CS) + (size_t)node * CS + off4);
        *(float4*)(&xl[nl * KP + slice * CS + off4]) = v;
    }

    int ct = tid & 31;
    int ng = tid >> 5;
    int c4 = ct * 4;
    float4 acc[4];
#pragma unroll
    for (int i = 0; i < 4; ++i) acc[i] = make_float4(0.f, 0.f, 0.f, 0.f);

#pragma unroll 1
    for (int p = 0; p < NPASS; ++p) {
        if (p > 0) __syncthreads();      // WAR on wl
        {
            const float4* Wsrc = (const float4*)(W + (size_t)p * KH * 128);
            float4* wl4 = (float4*)wl;
#pragma unroll 1
            for (int i = tid; i < KH * 32; i += 256) wl4[i] = Wsrc[i];
        }
        __syncthreads();                 // covers xl (p==0) + wl

#pragma unroll 1
        for (int k4 = 0; k4 < KH / 4; ++k4) {
            float4 wv0 = *(const float4*)(&wl[(k4 * 4 + 0) * 128 + c4]);
            float4 wv1 = *(const float4*)(&wl[(k4 * 4 + 1) * 128 + c4]);
            float4 wv2 = *(const float4*)(&wl[(k4 * 4 + 2) * 128 + c4]);
            float4 wv3 = *(const float4*)(&wl[(k4 * 4 + 3) * 128 + c4]);
#pragma unroll
            for (int i = 0; i < 4; ++i) {
                float4 xv = *(const float4*)(&xl[(ng * 4 + i) * KP + p * KH + k4 * 4]);
                acc[i].x += xv.x * wv0.x; acc[i].y += xv.x * wv0.y;
                acc[i].z += xv.x * wv0.z; acc[i].w += xv.x * wv0.w;
                acc[i].x += xv.y * wv1.x; acc[i].y += xv.y * wv1.y;
                acc[i].z += xv.y * wv1.z; acc[i].w += xv.y * wv1.w;
                acc[i].x += xv.z * wv2.x; acc[i].y += xv.z * wv2.y;
                acc[i].z += xv.z * wv2.z; acc[i].w += xv.z * wv2.w;
                acc[i].x += xv.w * wv3.x; acc[i].y += xv.w * wv3.y;
                acc[i].z += xv.w * wv3.z; acc[i].w += xv.w * wv3.w;
            }
        }
    }

    float4 ka = *(const float4*)(kA + c4);
    float4 kb = *(const float4*)(kB + c4);
#pragma unroll
    for (int i = 0; i < 4; ++i) {
        int node = base + ng * 4 + i;
        if (node >= n) continue;
        float4 a = acc[i];
        float4 v;
        v.x = fmaxf(a.x * ka.x + kb.x, 0.f);
        v.y = fmaxf(a.y * ka.y + kb.y, 0.f);
        v.z = fmaxf(a.z * ka.z + kb.z, 0.f);
        v.w = fmaxf(a.w * ka.w + kb.w, 0.f);
        size_t slot = (size_t)(c4 >> 4) * ((size_t)n * 16) + (size_t)node * 16 + (c4 & 15);
        if (RES) {
            float4 rv = *(const float4*)(res + slot);
            v.x += rv.x; v.y += rv.y; v.z += rv.z; v.w += rv.w;
        }
        *(float4*)(outs + slot) = v;
    }
}

// ---------------------------------------------------------------------------
// Per-graph mean-pool + final linear. batch is SORTED: graph g owns a
// contiguous node range found by binary search. No atomics anywhere.
__global__ __launch_bounds__(128) void k_poolfinal(
    const float* __restrict__ Hs, const int* __restrict__ batch,
    const float* __restrict__ Wf, const float* __restrict__ bf,
    float* __restrict__ out, int n) {
    int g = blockIdx.x;
    int t = threadIdx.x;
    int lo = 0, hi = n;
    while (lo < hi) { int m = (lo + hi) >> 1; if (batch[m] < g) lo = m + 1; else hi = m; }
    int start = lo;
    lo = 0; hi = n;
    while (lo < hi) { int m = (lo + hi) >> 1; if (batch[m] < g + 1) lo = m + 1; else hi = m; }
    int end = lo;

    const float* base = Hs + (size_t)(t >> 4) * ((size_t)n * 16) + (t & 15);
    float acc = 0.f;
    for (int i = start; i < end; ++i) acc += base[(size_t)i * 16];
    float v = acc * Wf[t];

    __shared__ float red[128];
    red[t] = v;
    __syncthreads();
    for (int s = 64; s > 0; s >>= 1) {
        if (t < s) red[t] += red[t + s];
        __syncthreads();
    }
    if (t == 0) out[g] = red[0] / fmaxf((float)(end - start), 1.f) + bf[0];
}

// ---------------------------------------------------------------------------
extern "C" void kernel_launch(void* const* d_in, const int* in_sizes, int n_in,
                              void* d_out, int out_size, void* d_ws, size_t ws_size,
                              hipStream_t stream) {
    const float* x     = (const float*)d_in[0];
    const int*   ei    = (const int*)d_in[1];
    const int*   src   = ei;
    const int*   dst   = ei + N_EDGES;
    const float* w     = (const float*)d_in[2];
    const int*   batch = (const int*)d_in[3];
    const float* W1 = (const float*)d_in[4];
    const float* b1 = (const float*)d_in[5];
    const float* W2 = (const float*)d_in[6];
    const float* b2 = (const float*)d_in[7];
    const float* W3 = (const float*)d_in[8];
    const float* b3 = (const float*)d_in[9];
    const float* Wf = (const float*)d_in[10];
    const float* bf = (const float*)d_in[11];
    const float* g1 = (const float*)d_in[12];
    const float* be1 = (const float*)d_in[13];
    const float* m1 = (const float*)d_in[14];
    const float* v1 = (const float*)d_in[15];
    const float* g2 = (const float*)d_in[16];
    const float* be2 = (const float*)d_in[17];
    const float* m2 = (const float*)d_in[18];
    const float* v2 = (const float*)d_in[19];
    const float* g3 = (const float*)d_in[20];
    const float* be3 = (const float*)d_in[21];
    const float* m3 = (const float*)d_in[22];
    const float* v3 = (const float*)d_in[23];

    float* out = (float*)d_out;

    // Workspace layout (all sections 16B-aligned)
    float* ws    = (float*)d_ws;
    float* out2s = ws;                                    // N*128 sliced-16 (L2 out / res / L3 out in-place)
    float* buf2  = out2s + (size_t)N_NODES * 128;         // N*128: agg2 (N*64) then agg3s
    float* agg2  = buf2;                                  // plain [node][64]
    int2*  csr   = (int2*)(buf2 + (size_t)N_NODES * 128); // E
    float* wdeg  = (float*)(csr + N_EDGES);               // N (becomes dinv)
    int*   cnt_i = (int*)(wdeg + N_NODES);                // N
    int*   cursor = cnt_i + N_NODES;                      // N (reused as aggx)
    float* aggx  = (float*)cursor;
    float* kA1   = (float*)(cursor + N_NODES);            // 64
    float* kB1   = kA1 + 64;                              // 64
    float* kA2   = kB1 + 64;                              // 128
    float* kB2   = kA2 + 128;                             // 128
    float* kA3   = kB2 + 128;                             // 128
    float* kB3   = kA3 + 128;                             // 128
    int*   offs  = (int*)(kB3 + 128);                     // N+1
    int*   bsum  = offs + N_NODES + 1;                    // SCAN_NB
    int*   bpre  = bsum + SCAN_NB;                        // SCAN_NB

    const int BS = 256;
    auto nb = [](long n) { return (int)((n + 255) / 256); };

    hipMemsetAsync(wdeg, 0, N_NODES * sizeof(float), stream);
    hipMemsetAsync(cnt_i, 0, N_NODES * sizeof(int), stream);

    // --- CSR build + degree norm ---
    k_degcnt<<<nb(N_EDGES), BS, 0, stream>>>(dst, w, wdeg, cnt_i, N_EDGES);
    k_scan1<<<SCAN_NB, 256, 0, stream>>>(cnt_i, bsum, N_NODES);
    k_scan2<<<1, 256, 0, stream>>>(bsum, bpre, SCAN_NB);
    k_scan3<<<SCAN_NB, 256, 0, stream>>>(cnt_i, bpre, offs, cursor, N_NODES);
    k_dinv<<<nb(N_NODES), BS, 0, stream>>>(wdeg, N_NODES);
    float* dinv = wdeg;
    k_fill<<<nb(N_EDGES), BS, 0, stream>>>(src, dst, w, dinv, cursor, csr, N_EDGES);
    k_bnprep_all<<<1, 320, 0, stream>>>(W1, b1, g1, be1, m1, v1, b2, g2, be2, m2, v2,
                                        b3, g3, be3, m3, v3, kA1, kB1, kA2, kB2, kA3, kB3);

    // --- Layer 1 aggregate (scalar) ---
    k_aggx<<<nb(N_NODES), BS, 0, stream>>>(offs, csr, x, dinv, aggx, N_NODES);

    // --- Layer 2: fused L1-matmul + aggregate (4 thr/node), then 64->128 matmul ---
    k_gather2F<<<nb((long)N_NODES * 4), BS, 0, stream>>>(
        offs, csr, aggx, dinv, kA1, kB1, agg2, N_NODES);
    k_mmT<64, 1, false><<<(N_NODES + 31) / 32, BS, 0, stream>>>(
        agg2, W2, kA2, kB2, nullptr, out2s, N_NODES);

    // --- Layer 3: sliced aggregate (1 thr/node/slice), matmul + relu + res ---
    k_gatherS16<<<8 * ((N_NODES + 255) / 256), BS, 0, stream>>>(
        offs, csr, out2s, dinv, buf2, N_NODES);
    k_mmT<128, 8, true><<<(N_NODES + 31) / 32, BS, 0, stream>>>(
        buf2, W3, kA3, kB3, out2s, out2s, N_NODES);

    // --- per-graph mean pool + final linear (batch sorted, no atomics) ---
    k_poolfinal<<<N_GRAPHS, 128, 0, stream>>>(out2s, batch, Wf, bf, out, N_NODES);
}

// Round 12
// 379.440 us; speedup vs baseline: 1.1133x; 1.1133x over previous
//
#include <hip/hip_runtime.h>

#define N_NODES  50000
#define N_EDGES  640000
#define N_GRAPHS 500
static constexpr float BN_EPS = 1e-5f;
#define SCAN_NB ((N_NODES + 255) / 256)   // 196 blocks

// ---------------------------------------------------------------------------
__global__ void k_degcnt(const int* __restrict__ dst, const float* __restrict__ w,
                         float* __restrict__ wdeg, int* __restrict__ cnt, int E) {
    int i = blockIdx.x * blockDim.x + threadIdx.x;
    if (i < E) {
        int d = dst[i];
        atomicAdd(&wdeg[d], w[i]);
        atomicAdd(&cnt[d], 1);
    }
}

__global__ void k_dinv(float* __restrict__ wdeg, int n) {
    int i = blockIdx.x * blockDim.x + threadIdx.x;
    if (i < n) wdeg[i] = rsqrtf(wdeg[i] + 1.0f);
}

// --- 3-phase hierarchical exclusive scan of cnt[N] -> offs[N+1] (+cursor) ---
__global__ void k_scan1(const int* __restrict__ cnt, int* __restrict__ bsum, int n) {
    __shared__ int red[256];
    int i = blockIdx.x * 256 + threadIdx.x;
    red[threadIdx.x] = (i < n) ? cnt[i] : 0;
    __syncthreads();
    for (int off = 128; off > 0; off >>= 1) {
        if (threadIdx.x < off) red[threadIdx.x] += red[threadIdx.x + off];
        __syncthreads();
    }
    if (threadIdx.x == 0) bsum[blockIdx.x] = red[0];
}

__global__ void k_scan2(const int* __restrict__ bsum, int* __restrict__ bpre, int nb) {
    __shared__ int part[256];
    int t = threadIdx.x;
    part[t] = (t < nb) ? bsum[t] : 0;
    __syncthreads();
    for (int off = 1; off < 256; off <<= 1) {
        int v = (t >= off) ? part[t - off] : 0;
        __syncthreads();
        part[t] += v;
        __syncthreads();
    }
    if (t < nb) bpre[t] = (t == 0) ? 0 : part[t - 1];
}

__global__ void k_scan3(const int* __restrict__ cnt, const int* __restrict__ bpre,
                        int* __restrict__ offs, int* __restrict__ cursor, int n) {
    __shared__ int part[256];
    int i = blockIdx.x * 256 + threadIdx.x;
    int t = threadIdx.x;
    int v = (i < n) ? cnt[i] : 0;
    part[t] = v;
    __syncthreads();
    for (int off = 1; off < 256; off <<= 1) {
        int u = (t >= off) ? part[t - off] : 0;
        __syncthreads();
        part[t] += u;
        __syncthreads();
    }
    int excl = bpre[blockIdx.x] + part[t] - v;
    if (i < n) {
        offs[i] = excl;
        cursor[i] = excl;
    }
    if (i == n - 1) offs[n] = N_EDGES;
}

__global__ void k_fill(const int* __restrict__ src, const int* __restrict__ dst,
                       const float* __restrict__ w, const float* __restrict__ dinv,
                       int* __restrict__ cursor, int2* __restrict__ csr, int E) {
    int e = blockIdx.x * blockDim.x + threadIdx.x;
    if (e < E) {
        int s = src[e], d = dst[e];
        int pos = atomicAdd(&cursor[d], 1);
        csr[pos] = make_int2(s, __float_as_int(dinv[s] * w[e] * dinv[d]));
    }
}

// Fold bias+BN into per-channel affine. Layer1 additionally folds W1 (rank-1).
__global__ void k_bnprep_all(
    const float* W1,
    const float* b1, const float* g1, const float* be1, const float* m1, const float* v1,
    const float* b2, const float* g2, const float* be2, const float* m2, const float* v2,
    const float* b3, const float* g3, const float* be3, const float* m3, const float* v3,
    float* kA1, float* kB1, float* kA2, float* kB2, float* kA3, float* kB3) {
    int t = threadIdx.x;
    if (t < 64) {
        float s = g1[t] * rsqrtf(v1[t] + BN_EPS);
        kA1[t] = W1[t] * s;
        kB1[t] = (b1[t] - m1[t]) * s + be1[t];
    } else if (t < 192) {
        int c = t - 64;
        float s = g2[c] * rsqrtf(v2[c] + BN_EPS);
        kA2[c] = s; kB2[c] = (b2[c] - m2[c]) * s + be2[c];
    } else if (t < 320) {
        int c = t - 192;
        float s = g3[c] * rsqrtf(v3[c] + BN_EPS);
        kA3[c] = s; kB3[c] = (b3[c] - m3[c]) * s + be3[c];
    }
}

// Layer-1 scalar aggregation over the 200KB x table (2-edge unrolled).
__global__ void k_aggx(const int* __restrict__ offs, const int2* __restrict__ csr,
                       const float* __restrict__ x, const float* __restrict__ dinv,
                       float* __restrict__ aggx, int n) {
    int i = blockIdx.x * blockDim.x + threadIdx.x;
    if (i >= n) return;
    float acc = 0.f;
    int e0 = offs[i], e1 = offs[i + 1];
    int j = e0;
    for (; j + 1 < e1; j += 2) {
        int2 ea = csr[j];
        int2 eb = csr[j + 1];
        acc += x[ea.x] * __int_as_float(ea.y) + x[eb.x] * __int_as_float(eb.y);
    }
    if (j < e1) {
        int2 e = csr[j];
        acc += x[e.x] * __int_as_float(e.y);
    }
    float di = dinv[i];
    aggx[i] = acc + x[i] * di * di;
}

// ---------------------------------------------------------------------------
// Fused layer-1-matmul + layer-2 aggregation. 16 threads/node, 4 ch each
// (r10 winning form — r11's 4-thr/node variant was neutral-to-worse).
// 2-edge unroll for 2x memory-level parallelism on the csr->aggx chain.
__global__ void k_gather2F(const int* __restrict__ offs, const int2* __restrict__ csr,
                           const float* __restrict__ aggx, const float* __restrict__ dinv,
                           const float* __restrict__ kA1, const float* __restrict__ kB1,
                           float* __restrict__ agg2, int n) {
    int gid = blockIdx.x * blockDim.x + threadIdx.x;
    int node = gid >> 4;
    if (node >= n) return;
    int c4 = (gid & 15) * 4;
    float4 wa = *(const float4*)(kA1 + c4);
    float4 wb = *(const float4*)(kB1 + c4);
    float4 acc = {0.f, 0.f, 0.f, 0.f};
    int e0 = offs[node], e1 = offs[node + 1];
    int j = e0;
    for (; j + 1 < e1; j += 2) {
        int2 ea = csr[j];
        int2 eb = csr[j + 1];
        float aa = aggx[ea.x];
        float ab = aggx[eb.x];
        float nma = __int_as_float(ea.y);
        float nmb = __int_as_float(eb.y);
        acc.x += nma * fmaxf(aa * wa.x + wb.x, 0.f) + nmb * fmaxf(ab * wa.x + wb.x, 0.f);
        acc.y += nma * fmaxf(aa * wa.y + wb.y, 0.f) + nmb * fmaxf(ab * wa.y + wb.y, 0.f);
        acc.z += nma * fmaxf(aa * wa.z + wb.z, 0.f) + nmb * fmaxf(ab * wa.z + wb.z, 0.f);
        acc.w += nma * fmaxf(aa * wa.w + wb.w, 0.f) + nmb * fmaxf(ab * wa.w + wb.w, 0.f);
    }
    if (j < e1) {
        int2 e = csr[j];
        float a = aggx[e.x];
        float nm = __int_as_float(e.y);
        acc.x += nm * fmaxf(a * wa.x + wb.x, 0.f);
        acc.y += nm * fmaxf(a * wa.y + wb.y, 0.f);
        acc.z += nm * fmaxf(a * wa.z + wb.z, 0.f);
        acc.w += nm * fmaxf(a * wa.w + wb.w, 0.f);
    }
    float di = dinv[node];
    float d2 = di * di;
    float a = aggx[node];
    acc.x += d2 * fmaxf(a * wa.x + wb.x, 0.f);
    acc.y += d2 * fmaxf(a * wa.y + wb.y, 0.f);
    acc.z += d2 * fmaxf(a * wa.z + wb.z, 0.f);
    acc.w += d2 * fmaxf(a * wa.w + wb.w, 0.f);
    *(float4*)(agg2 + (size_t)node * 64 + c4) = acc;
}

// ---------------------------------------------------------------------------
// Channel-sliced gather (layer 3): slice = blockIdx%8 -> XCD-local 3.2MB table.
// 4 threads/node (r10 winning form: 4 lanes cover one 64B row per edge —
// coalesced; r11's 1-thr/node caused 4x line amplification, FETCH 97->233MB).
// 2-edge unroll for 2x MLP on the csr->gather dependency chain.
__global__ void k_gatherS16(const int* __restrict__ offs, const int2* __restrict__ csr,
                            const float* __restrict__ Hs, const float* __restrict__ dinv,
                            float* __restrict__ aggs, int n) {
    int slice = blockIdx.x & 7;
    int node = (blockIdx.x >> 3) * 64 + threadIdx.x / 4;
    if (node >= n) return;
    int cq = (threadIdx.x % 4) * 4;
    const float* Hb = Hs + (size_t)slice * ((size_t)n * 16);
    float4 acc = {0.f, 0.f, 0.f, 0.f};
    int e0 = offs[node], e1 = offs[node + 1];
    int j = e0;
    for (; j + 1 < e1; j += 2) {
        int2 ea = csr[j];
        int2 eb = csr[j + 1];
        float nma = __int_as_float(ea.y);
        float nmb = __int_as_float(eb.y);
        float4 ha = *(const float4*)(Hb + (size_t)ea.x * 16 + cq);
        float4 hb = *(const float4*)(Hb + (size_t)eb.x * 16 + cq);
        acc.x += ha.x * nma + hb.x * nmb;
        acc.y += ha.y * nma + hb.y * nmb;
        acc.z += ha.z * nma + hb.z * nmb;
        acc.w += ha.w * nma + hb.w * nmb;
    }
    if (j < e1) {
        int2 e = csr[j];
        float nm = __int_as_float(e.y);
        float4 hv = *(const float4*)(Hb + (size_t)e.x * 16 + cq);
        acc.x += hv.x * nm;
        acc.y += hv.y * nm;
        acc.z += hv.z * nm;
        acc.w += hv.w * nm;
    }
    float di = dinv[node];
    float d2 = di * di;
    float4 hv = *(const float4*)(Hb + (size_t)node * 16 + cq);
    acc.x += hv.x * d2;
    acc.y += hv.y * d2;
    acc.z += hv.z * d2;
    acc.w += hv.w * d2;
    *(float4*)(aggs + (size_t)slice * ((size_t)n * 16) + (size_t)node * 16 + cq) = acc;
}

// ---------------------------------------------------------------------------
// Register-tiled matmul: 32 nodes/block, x-tile AND W staged in LDS.
// k4/p loops pinned rolled (#pragma unroll 1) — r6/r8 spilled at 256 VGPR when
// the compiler unrolled a load loop. RES=true adds residual and writes
// IN-PLACE (outs may alias res — each slot owned by exactly one thread).
template <int K, int S, bool RES>
__global__ __launch_bounds__(256) void k_mmT(
    const float* __restrict__ Xs, const float* __restrict__ W,
    const float* __restrict__ kA, const float* __restrict__ kB,
    const float* __restrict__ res, float* __restrict__ outs, int n) {
    constexpr int CS = K / S;
    constexpr int KP = K + 4;            // padded LDS row stride (floats)
    constexpr int KH = 64;               // W half-pass rows
    constexpr int NPASS = K / KH;
    __shared__ float xl[32 * KP];
    __shared__ float wl[KH * 128];       // 32 KB
    int base = blockIdx.x * 32;
    int tid = threadIdx.x;
    constexpr int TOT4 = 32 * K / 4;
    constexpr int SL4 = 32 * CS / 4;
    for (int i = tid; i < TOT4; i += 256) {
        int slice = i / SL4;
        int rem = i - slice * SL4;
        int nl = rem / (CS / 4);
        int off4 = (rem % (CS / 4)) * 4;
        int node = base + nl;
        float4 v = {0.f, 0.f, 0.f, 0.f};
        if (node < n)
            v = *(const float4*)(Xs + (size_t)slice * ((size_t)n * CS) + (size_t)node * CS + off4);
        *(float4*)(&xl[nl * KP + slice * CS + off4]) = v;
    }

    int ct = tid & 31;
    int ng = tid >> 5;
    int c4 = ct * 4;
    float4 acc[4];
#pragma unroll
    for (int i = 0; i < 4; ++i) acc[i] = make_float4(0.f, 0.f, 0.f, 0.f);

#pragma unroll 1
    for (int p = 0; p < NPASS; ++p) {
        if (p > 0) __syncthreads();      // WAR on wl
        {
            const float4* Wsrc = (const float4*)(W + (size_t)p * KH * 128);
            float4* wl4 = (float4*)wl;
#pragma unroll 1
            for (int i = tid; i < KH * 32; i += 256) wl4[i] = Wsrc[i];
        }
        __syncthreads();                 // covers xl (p==0) + wl

#pragma unroll 1
        for (int k4 = 0; k4 < KH / 4; ++k4) {
            float4 wv0 = *(const float4*)(&wl[(k4 * 4 + 0) * 128 + c4]);
            float4 wv1 = *(const float4*)(&wl[(k4 * 4 + 1) * 128 + c4]);
            float4 wv2 = *(const float4*)(&wl[(k4 * 4 + 2) * 128 + c4]);
            float4 wv3 = *(const float4*)(&wl[(k4 * 4 + 3) * 128 + c4]);
#pragma unroll
            for (int i = 0; i < 4; ++i) {
                float4 xv = *(const float4*)(&xl[(ng * 4 + i) * KP + p * KH + k4 * 4]);
                acc[i].x += xv.x * wv0.x; acc[i].y += xv.x * wv0.y;
                acc[i].z += xv.x * wv0.z; acc[i].w += xv.x * wv0.w;
                acc[i].x += xv.y * wv1.x; acc[i].y += xv.y * wv1.y;
                acc[i].z += xv.y * wv1.z; acc[i].w += xv.y * wv1.w;
                acc[i].x += xv.z * wv2.x; acc[i].y += xv.z * wv2.y;
                acc[i].z += xv.z * wv2.z; acc[i].w += xv.z * wv2.w;
                acc[i].x += xv.w * wv3.x; acc[i].y += xv.w * wv3.y;
                acc[i].z += xv.w * wv3.z; acc[i].w += xv.w * wv3.w;
            }
        }
    }

    float4 ka = *(const float4*)(kA + c4);
    float4 kb = *(const float4*)(kB + c4);
#pragma unroll
    for (int i = 0; i < 4; ++i) {
        int node = base + ng * 4 + i;
        if (node >= n) continue;
        float4 a = acc[i];
        float4 v;
        v.x = fmaxf(a.x * ka.x + kb.x, 0.f);
        v.y = fmaxf(a.y * ka.y + kb.y, 0.f);
        v.z = fmaxf(a.z * ka.z + kb.z, 0.f);
        v.w = fmaxf(a.w * ka.w + kb.w, 0.f);
        size_t slot = (size_t)(c4 >> 4) * ((size_t)n * 16) + (size_t)node * 16 + (c4 & 15);
        if (RES) {
            float4 rv = *(const float4*)(res + slot);
            v.x += rv.x; v.y += rv.y; v.z += rv.z; v.w += rv.w;
        }
        *(float4*)(outs + slot) = v;
    }
}

// ---------------------------------------------------------------------------
// Per-graph mean-pool + final linear. batch is SORTED: graph g owns a
// contiguous node range found by binary search. No atomics anywhere.
__global__ __launch_bounds__(128) void k_poolfinal(
    const float* __restrict__ Hs, const int* __restrict__ batch,
    const float* __restrict__ Wf, const float* __restrict__ bf,
    float* __restrict__ out, int n) {
    int g = blockIdx.x;
    int t = threadIdx.x;
    int lo = 0, hi = n;
    while (lo < hi) { int m = (lo + hi) >> 1; if (batch[m] < g) lo = m + 1; else hi = m; }
    int start = lo;
    lo = 0; hi = n;
    while (lo < hi) { int m = (lo + hi) >> 1; if (batch[m] < g + 1) lo = m + 1; else hi = m; }
    int end = lo;

    const float* base = Hs + (size_t)(t >> 4) * ((size_t)n * 16) + (t & 15);
    float acc = 0.f;
    for (int i = start; i < end; ++i) acc += base[(size_t)i * 16];
    float v = acc * Wf[t];

    __shared__ float red[128];
    red[t] = v;
    __syncthreads();
    for (int s = 64; s > 0; s >>= 1) {
        if (t < s) red[t] += red[t + s];
        __syncthreads();
    }
    if (t == 0) out[g] = red[0] / fmaxf((float)(end - start), 1.f) + bf[0];
}

// ---------------------------------------------------------------------------
extern "C" void kernel_launch(void* const* d_in, const int* in_sizes, int n_in,
                              void* d_out, int out_size, void* d_ws, size_t ws_size,
                              hipStream_t stream) {
    const float* x     = (const float*)d_in[0];
    const int*   ei    = (const int*)d_in[1];
    const int*   src   = ei;
    const int*   dst   = ei + N_EDGES;
    const float* w     = (const float*)d_in[2];
    const int*   batch = (const int*)d_in[3];
    const float* W1 = (const float*)d_in[4];
    const float* b1 = (const float*)d_in[5];
    const float* W2 = (const float*)d_in[6];
    const float* b2 = (const float*)d_in[7];
    const float* W3 = (const float*)d_in[8];
    const float* b3 = (const float*)d_in[9];
    const float* Wf = (const float*)d_in[10];
    const float* bf = (const float*)d_in[11];
    const float* g1 = (const float*)d_in[12];
    const float* be1 = (const float*)d_in[13];
    const float* m1 = (const float*)d_in[14];
    const float* v1 = (const float*)d_in[15];
    const float* g2 = (const float*)d_in[16];
    const float* be2 = (const float*)d_in[17];
    const float* m2 = (const float*)d_in[18];
    const float* v2 = (const float*)d_in[19];
    const float* g3 = (const float*)d_in[20];
    const float* be3 = (const float*)d_in[21];
    const float* m3 = (const float*)d_in[22];
    const float* v3 = (const float*)d_in[23];

    float* out = (float*)d_out;

    // Workspace layout (all sections 16B-aligned)
    float* ws    = (float*)d_ws;
    float* out2s = ws;                                    // N*128 sliced-16 (L2 out / res / L3 out in-place)
    float* buf2  = out2s + (size_t)N_NODES * 128;         // N*128: agg2 (N*64) then agg3s
    float* agg2  = buf2;                                  // plain [node][64]
    int2*  csr   = (int2*)(buf2 + (size_t)N_NODES * 128); // E
    float* wdeg  = (float*)(csr + N_EDGES);               // N (becomes dinv)
    int*   cnt_i = (int*)(wdeg + N_NODES);                // N
    int*   cursor = cnt_i + N_NODES;                      // N (reused as aggx)
    float* aggx  = (float*)cursor;
    float* kA1   = (float*)(cursor + N_NODES);            // 64
    float* kB1   = kA1 + 64;                              // 64
    float* kA2   = kB1 + 64;                              // 128
    float* kB2   = kA2 + 128;                             // 128
    float* kA3   = kB2 + 128;                             // 128
    float* kB3   = kA3 + 128;                             // 128
    int*   offs  = (int*)(kB3 + 128);                     // N+1
    int*   bsum  = offs + N_NODES + 1;                    // SCAN_NB
    int*   bpre  = bsum + SCAN_NB;                        // SCAN_NB

    const int BS = 256;
    auto nb = [](long n) { return (int)((n + 255) / 256); };

    hipMemsetAsync(wdeg, 0, N_NODES * sizeof(float), stream);
    hipMemsetAsync(cnt_i, 0, N_NODES * sizeof(int), stream);

    // --- CSR build + degree norm ---
    k_degcnt<<<nb(N_EDGES), BS, 0, stream>>>(dst, w, wdeg, cnt_i, N_EDGES);
    k_scan1<<<SCAN_NB, 256, 0, stream>>>(cnt_i, bsum, N_NODES);
    k_scan2<<<1, 256, 0, stream>>>(bsum, bpre, SCAN_NB);
    k_scan3<<<SCAN_NB, 256, 0, stream>>>(cnt_i, bpre, offs, cursor, N_NODES);
    k_dinv<<<nb(N_NODES), BS, 0, stream>>>(wdeg, N_NODES);
    float* dinv = wdeg;
    k_fill<<<nb(N_EDGES), BS, 0, stream>>>(src, dst, w, dinv, cursor, csr, N_EDGES);
    k_bnprep_all<<<1, 320, 0, stream>>>(W1, b1, g1, be1, m1, v1, b2, g2, be2, m2, v2,
                                        b3, g3, be3, m3, v3, kA1, kB1, kA2, kB2, kA3, kB3);

    // --- Layer 1 aggregate (scalar) ---
    k_aggx<<<nb(N_NODES), BS, 0, stream>>>(offs, csr, x, dinv, aggx, N_NODES);

    // --- Layer 2: fused L1-matmul + aggregate (16 thr/node), then 64->128 matmul ---
    k_gather2F<<<nb((long)N_NODES * 16), BS, 0, stream>>>(
        offs, csr, aggx, dinv, kA1, kB1, agg2, N_NODES);
    k_mmT<64, 1, false><<<(N_NODES + 31) / 32, BS, 0, stream>>>(
        agg2, W2, kA2, kB2, nullptr, out2s, N_NODES);

    // --- Layer 3: sliced aggregate (4 thr/node/slice), matmul + relu + res ---
    k_gatherS16<<<8 * ((N_NODES + 63) / 64), BS, 0, stream>>>(
        offs, csr, out2s, dinv, buf2, N_NODES);
    k_mmT<128, 8, true><<<(N_NODES + 31) / 32, BS, 0, stream>>>(
        buf2, W3, kA3, kB3, out2s, out2s, N_NODES);

    // --- per-graph mean pool + final linear (batch sorted, no atomics) ---
    k_poolfinal<<<N_GRAPHS, 128, 0, stream>>>(out2s, batch, Wf, bf, out, N_NODES);
}

// Round 13
// 328.518 us; speedup vs baseline: 1.2859x; 1.1550x over previous
//
#include <hip/hip_runtime.h>

#define N_NODES  50000
#define N_EDGES  640000
#define N_GRAPHS 500
static constexpr float BN_EPS = 1e-5f;
#define SCAN_NB ((N_NODES + 255) / 256)   // 196 blocks
static constexpr float FIX = 16777216.0f;       // 2^24
static constexpr float FIXINV = 5.9604644775390625e-8f;  // 2^-24

// ---------------------------------------------------------------------------
// Packed degree/count: one 64-bit atomic per edge. hi32 = edge count,
// lo32 = weighted degree in 24-bit fixed point (max deg ~45 -> sum < 2^31,
// no carry into hi; quantization error ~4e-7 << 6.5e-3 threshold).
// Returned old value gives this edge's rank within its dst -> seq[] makes
// k_fill atomic-free.
__global__ void k_degcnt(const int* __restrict__ dst, const float* __restrict__ w,
                         unsigned long long* __restrict__ packed,
                         int* __restrict__ seq, int E) {
    int i = blockIdx.x * blockDim.x + threadIdx.x;
    if (i < E) {
        int d = dst[i];
        unsigned uf = (unsigned)(w[i] * FIX + 0.5f);
        unsigned long long old =
            atomicAdd(&packed[d], (1ULL << 32) | (unsigned long long)uf);
        seq[i] = (int)(old >> 32);
    }
}

__global__ void k_dinv(const unsigned long long* __restrict__ packed,
                       float* __restrict__ dinv, int n) {
    int i = blockIdx.x * blockDim.x + threadIdx.x;
    if (i < n) {
        float wdeg = (float)(unsigned)(packed[i] & 0xFFFFFFFFu) * FIXINV;
        dinv[i] = rsqrtf(wdeg + 1.0f);
    }
}

// --- 3-phase hierarchical exclusive scan of counts (packed hi32) -> offs ---
__global__ void k_scan1(const unsigned long long* __restrict__ packed,
                        int* __restrict__ bsum, int n) {
    __shared__ int red[256];
    int i = blockIdx.x * 256 + threadIdx.x;
    red[threadIdx.x] = (i < n) ? (int)(packed[i] >> 32) : 0;
    __syncthreads();
    for (int off = 128; off > 0; off >>= 1) {
        if (threadIdx.x < off) red[threadIdx.x] += red[threadIdx.x + off];
        __syncthreads();
    }
    if (threadIdx.x == 0) bsum[blockIdx.x] = red[0];
}

__global__ void k_scan2(const int* __restrict__ bsum, int* __restrict__ bpre, int nb) {
    __shared__ int part[256];
    int t = threadIdx.x;
    part[t] = (t < nb) ? bsum[t] : 0;
    __syncthreads();
    for (int off = 1; off < 256; off <<= 1) {
        int v = (t >= off) ? part[t - off] : 0;
        __syncthreads();
        part[t] += v;
        __syncthreads();
    }
    if (t < nb) bpre[t] = (t == 0) ? 0 : part[t - 1];
}

__global__ void k_scan3(const unsigned long long* __restrict__ packed,
                        const int* __restrict__ bpre, int* __restrict__ offs, int n) {
    __shared__ int part[256];
    int i = blockIdx.x * 256 + threadIdx.x;
    int t = threadIdx.x;
    int v = (i < n) ? (int)(packed[i] >> 32) : 0;
    part[t] = v;
    __syncthreads();
    for (int off = 1; off < 256; off <<= 1) {
        int u = (t >= off) ? part[t - off] : 0;
        __syncthreads();
        part[t] += u;
        __syncthreads();
    }
    int excl = bpre[blockIdx.x] + part[t] - v;
    if (i < n) offs[i] = excl;
    if (i == n - 1) offs[n] = N_EDGES;
}

// Atomic-free CSR fill: pos = offs[dst] + seq[e].
__global__ void k_fill(const int* __restrict__ src, const int* __restrict__ dst,
                       const float* __restrict__ w, const float* __restrict__ dinv,
                       const int* __restrict__ offs, const int* __restrict__ seq,
                       int2* __restrict__ csr, int E) {
    int e = blockIdx.x * blockDim.x + threadIdx.x;
    if (e < E) {
        int s = src[e], d = dst[e];
        int pos = offs[d] + seq[e];
        csr[pos] = make_int2(s, __float_as_int(dinv[s] * w[e] * dinv[d]));
    }
}

// Fold bias+BN into per-channel affine. Layer1 additionally folds W1 (rank-1).
__global__ void k_bnprep_all(
    const float* W1,
    const float* b1, const float* g1, const float* be1, const float* m1, const float* v1,
    const float* b2, const float* g2, const float* be2, const float* m2, const float* v2,
    const float* b3, const float* g3, const float* be3, const float* m3, const float* v3,
    float* kA1, float* kB1, float* kA2, float* kB2, float* kA3, float* kB3) {
    int t = threadIdx.x;
    if (t < 64) {
        float s = g1[t] * rsqrtf(v1[t] + BN_EPS);
        kA1[t] = W1[t] * s;
        kB1[t] = (b1[t] - m1[t]) * s + be1[t];
    } else if (t < 192) {
        int c = t - 64;
        float s = g2[c] * rsqrtf(v2[c] + BN_EPS);
        kA2[c] = s; kB2[c] = (b2[c] - m2[c]) * s + be2[c];
    } else if (t < 320) {
        int c = t - 192;
        float s = g3[c] * rsqrtf(v3[c] + BN_EPS);
        kA3[c] = s; kB3[c] = (b3[c] - m3[c]) * s + be3[c];
    }
}

// Layer-1 scalar aggregation over the 200KB x table (2-edge unrolled).
__global__ void k_aggx(const int* __restrict__ offs, const int2* __restrict__ csr,
                       const float* __restrict__ x, const float* __restrict__ dinv,
                       float* __restrict__ aggx, int n) {
    int i = blockIdx.x * blockDim.x + threadIdx.x;
    if (i >= n) return;
    float acc = 0.f;
    int e0 = offs[i], e1 = offs[i + 1];
    int j = e0;
    for (; j + 1 < e1; j += 2) {
        int2 ea = csr[j];
        int2 eb = csr[j + 1];
        acc += x[ea.x] * __int_as_float(ea.y) + x[eb.x] * __int_as_float(eb.y);
    }
    if (j < e1) {
        int2 e = csr[j];
        acc += x[e.x] * __int_as_float(e.y);
    }
    float di = dinv[i];
    aggx[i] = acc + x[i] * di * di;
}

// ---------------------------------------------------------------------------
// Fused layer-1-matmul + layer-2 aggregation. 16 threads/node, 4 ch each
// (r10 winning form). 2-edge unroll for MLP on the csr->aggx chain.
__global__ void k_gather2F(const int* __restrict__ offs, const int2* __restrict__ csr,
                           const float* __restrict__ aggx, const float* __restrict__ dinv,
                           const float* __restrict__ kA1, const float* __restrict__ kB1,
                           float* __restrict__ agg2, int n) {
    int gid = blockIdx.x * blockDim.x + threadIdx.x;
    int node = gid >> 4;
    if (node >= n) return;
    int c4 = (gid & 15) * 4;
    float4 wa = *(const float4*)(kA1 + c4);
    float4 wb = *(const float4*)(kB1 + c4);
    float4 acc = {0.f, 0.f, 0.f, 0.f};
    int e0 = offs[node], e1 = offs[node + 1];
    int j = e0;
    for (; j + 1 < e1; j += 2) {
        int2 ea = csr[j];
        int2 eb = csr[j + 1];
        float aa = aggx[ea.x];
        float ab = aggx[eb.x];
        float nma = __int_as_float(ea.y);
        float nmb = __int_as_float(eb.y);
        acc.x += nma * fmaxf(aa * wa.x + wb.x, 0.f) + nmb * fmaxf(ab * wa.x + wb.x, 0.f);
        acc.y += nma * fmaxf(aa * wa.y + wb.y, 0.f) + nmb * fmaxf(ab * wa.y + wb.y, 0.f);
        acc.z += nma * fmaxf(aa * wa.z + wb.z, 0.f) + nmb * fmaxf(ab * wa.z + wb.z, 0.f);
        acc.w += nma * fmaxf(aa * wa.w + wb.w, 0.f) + nmb * fmaxf(ab * wa.w + wb.w, 0.f);
    }
    if (j < e1) {
        int2 e = csr[j];
        float a = aggx[e.x];
        float nm = __int_as_float(e.y);
        acc.x += nm * fmaxf(a * wa.x + wb.x, 0.f);
        acc.y += nm * fmaxf(a * wa.y + wb.y, 0.f);
        acc.z += nm * fmaxf(a * wa.z + wb.z, 0.f);
        acc.w += nm * fmaxf(a * wa.w + wb.w, 0.f);
    }
    float di = dinv[node];
    float d2 = di * di;
    float a = aggx[node];
    acc.x += d2 * fmaxf(a * wa.x + wb.x, 0.f);
    acc.y += d2 * fmaxf(a * wa.y + wb.y, 0.f);
    acc.z += d2 * fmaxf(a * wa.z + wb.z, 0.f);
    acc.w += d2 * fmaxf(a * wa.w + wb.w, 0.f);
    *(float4*)(agg2 + (size_t)node * 64 + c4) = acc;
}

// ---------------------------------------------------------------------------
// Channel-sliced gather (layer 3): slice = blockIdx%8 -> XCD-local 3.2MB table.
// 4 threads/node (coalesced 64B row per edge), 2-edge unroll.
__global__ void k_gatherS16(const int* __restrict__ offs, const int2* __restrict__ csr,
                            const float* __restrict__ Hs, const float* __restrict__ dinv,
                            float* __restrict__ aggs, int n) {
    int slice = blockIdx.x & 7;
    int node = (blockIdx.x >> 3) * 64 + threadIdx.x / 4;
    if (node >= n) return;
    int cq = (threadIdx.x % 4) * 4;
    const float* Hb = Hs + (size_t)slice * ((size_t)n * 16);
    float4 acc = {0.f, 0.f, 0.f, 0.f};
    int e0 = offs[node], e1 = offs[node + 1];
    int j = e0;
    for (; j + 1 < e1; j += 2) {
        int2 ea = csr[j];
        int2 eb = csr[j + 1];
        float nma = __int_as_float(ea.y);
        float nmb = __int_as_float(eb.y);
        float4 ha = *(const float4*)(Hb + (size_t)ea.x * 16 + cq);
        float4 hb = *(const float4*)(Hb + (size_t)eb.x * 16 + cq);
        acc.x += ha.x * nma + hb.x * nmb;
        acc.y += ha.y * nma + hb.y * nmb;
        acc.z += ha.z * nma + hb.z * nmb;
        acc.w += ha.w * nma + hb.w * nmb;
    }
    if (j < e1) {
        int2 e = csr[j];
        float nm = __int_as_float(e.y);
        float4 hv = *(const float4*)(Hb + (size_t)e.x * 16 + cq);
        acc.x += hv.x * nm;
        acc.y += hv.y * nm;
        acc.z += hv.z * nm;
        acc.w += hv.w * nm;
    }
    float di = dinv[node];
    float d2 = di * di;
    float4 hv = *(const float4*)(Hb + (size_t)node * 16 + cq);
    acc.x += hv.x * d2;
    acc.y += hv.y * d2;
    acc.z += hv.z * d2;
    acc.w += hv.w * d2;
    *(float4*)(aggs + (size_t)slice * ((size_t)n * 16) + (size_t)node * 16 + cq) = acc;
}

// ---------------------------------------------------------------------------
// Register-tiled matmul: 32 nodes/block, x-tile AND W staged in LDS.
// k4/p loops pinned rolled (#pragma unroll 1) — r6/r8 spilled at 256 VGPR when
// the compiler unrolled a load loop. RES=true adds residual and writes
// IN-PLACE (outs may alias res — each slot owned by exactly one thread).
template <int K, int S, bool RES>
__global__ __launch_bounds__(256) void k_mmT(
    const float* __restrict__ Xs, const float* __restrict__ W,
    const float* __restrict__ kA, const float* __restrict__ kB,
    const float* __restrict__ res, float* __restrict__ outs, int n) {
    constexpr int CS = K / S;
    constexpr int KP = K + 4;            // padded LDS row stride (floats)
    constexpr int KH = 64;               // W half-pass rows
    constexpr int NPASS = K / KH;
    __shared__ float xl[32 * KP];
    __shared__ float wl[KH * 128];       // 32 KB
    int base = blockIdx.x * 32;
    int tid = threadIdx.x;
    constexpr int TOT4 = 32 * K / 4;
    constexpr int SL4 = 32 * CS / 4;
    for (int i = tid; i < TOT4; i += 256) {
        int slice = i / SL4;
        int rem = i - slice * SL4;
        int nl = rem / (CS / 4);
        int off4 = (rem % (CS / 4)) * 4;
        int node = base + nl;
        float4 v = {0.f, 0.f, 0.f, 0.f};
        if (node < n)
            v = *(const float4*)(Xs + (size_t)slice * ((size_t)n * CS) + (size_t)node * CS + off4);
        *(float4*)(&xl[nl * KP + slice * CS + off4]) = v;
    }

    int ct = tid & 31;
    int ng = tid >> 5;
    int c4 = ct * 4;
    float4 acc[4];
#pragma unroll
    for (int i = 0; i < 4; ++i) acc[i] = make_float4(0.f, 0.f, 0.f, 0.f);

#pragma unroll 1
    for (int p = 0; p < NPASS; ++p) {
        if (p > 0) __syncthreads();      // WAR on wl
        {
            const float4* Wsrc = (const float4*)(W + (size_t)p * KH * 128);
            float4* wl4 = (float4*)wl;
#pragma unroll 1
            for (int i = tid; i < KH * 32; i += 256) wl4[i] = Wsrc[i];
        }
        __syncthreads();                 // covers xl (p==0) + wl

#pragma unroll 1
        for (int k4 = 0; k4 < KH / 4; ++k4) {
            float4 wv0 = *(const float4*)(&wl[(k4 * 4 + 0) * 128 + c4]);
            float4 wv1 = *(const float4*)(&wl[(k4 * 4 + 1) * 128 + c4]);
            float4 wv2 = *(const float4*)(&wl[(k4 * 4 + 2) * 128 + c4]);
            float4 wv3 = *(const float4*)(&wl[(k4 * 4 + 3) * 128 + c4]);
#pragma unroll
            for (int i = 0; i < 4; ++i) {
                float4 xv = *(const float4*)(&xl[(ng * 4 + i) * KP + p * KH + k4 * 4]);
                acc[i].x += xv.x * wv0.x; acc[i].y += xv.x * wv0.y;
                acc[i].z += xv.x * wv0.z; acc[i].w += xv.x * wv0.w;
                acc[i].x += xv.y * wv1.x; acc[i].y += xv.y * wv1.y;
                acc[i].z += xv.y * wv1.z; acc[i].w += xv.y * wv1.w;
                acc[i].x += xv.z * wv2.x; acc[i].y += xv.z * wv2.y;
                acc[i].z += xv.z * wv2.z; acc[i].w += xv.z * wv2.w;
                acc[i].x += xv.w * wv3.x; acc[i].y += xv.w * wv3.y;
                acc[i].z += xv.w * wv3.z; acc[i].w += xv.w * wv3.w;
            }
        }
    }

    float4 ka = *(const float4*)(kA + c4);
    float4 kb = *(const float4*)(kB + c4);
#pragma unroll
    for (int i = 0; i < 4; ++i) {
        int node = base + ng * 4 + i;
        if (node >= n) continue;
        float4 a = acc[i];
        float4 v;
        v.x = fmaxf(a.x * ka.x + kb.x, 0.f);
        v.y = fmaxf(a.y * ka.y + kb.y, 0.f);
        v.z = fmaxf(a.z * ka.z + kb.z, 0.f);
        v.w = fmaxf(a.w * ka.w + kb.w, 0.f);
        size_t slot = (size_t)(c4 >> 4) * ((size_t)n * 16) + (size_t)node * 16 + (c4 & 15);
        if (RES) {
            float4 rv = *(const float4*)(res + slot);
            v.x += rv.x; v.y += rv.y; v.z += rv.z; v.w += rv.w;
        }
        *(float4*)(outs + slot) = v;
    }
}

// ---------------------------------------------------------------------------
// Per-graph mean-pool + final linear. batch is SORTED: graph g owns a
// contiguous node range found by binary search. No atomics anywhere.
__global__ __launch_bounds__(128) void k_poolfinal(
    const float* __restrict__ Hs, const int* __restrict__ batch,
    const float* __restrict__ Wf, const float* __restrict__ bf,
    float* __restrict__ out, int n) {
    int g = blockIdx.x;
    int t = threadIdx.x;
    int lo = 0, hi = n;
    while (lo < hi) { int m = (lo + hi) >> 1; if (batch[m] < g) lo = m + 1; else hi = m; }
    int start = lo;
    lo = 0; hi = n;
    while (lo < hi) { int m = (lo + hi) >> 1; if (batch[m] < g + 1) lo = m + 1; else hi = m; }
    int end = lo;

    const float* base = Hs + (size_t)(t >> 4) * ((size_t)n * 16) + (t & 15);
    float acc = 0.f;
    for (int i = start; i < end; ++i) acc += base[(size_t)i * 16];
    float v = acc * Wf[t];

    __shared__ float red[128];
    red[t] = v;
    __syncthreads();
    for (int s = 64; s > 0; s >>= 1) {
        if (t < s) red[t] += red[t + s];
        __syncthreads();
    }
    if (t == 0) out[g] = red[0] / fmaxf((float)(end - start), 1.f) + bf[0];
}

// ---------------------------------------------------------------------------
extern "C" void kernel_launch(void* const* d_in, const int* in_sizes, int n_in,
                              void* d_out, int out_size, void* d_ws, size_t ws_size,
                              hipStream_t stream) {
    const float* x     = (const float*)d_in[0];
    const int*   ei    = (const int*)d_in[1];
    const int*   src   = ei;
    const int*   dst   = ei + N_EDGES;
    const float* w     = (const float*)d_in[2];
    const int*   batch = (const int*)d_in[3];
    const float* W1 = (const float*)d_in[4];
    const float* b1 = (const float*)d_in[5];
    const float* W2 = (const float*)d_in[6];
    const float* b2 = (const float*)d_in[7];
    const float* W3 = (const float*)d_in[8];
    const float* b3 = (const float*)d_in[9];
    const float* Wf = (const float*)d_in[10];
    const float* bf = (const float*)d_in[11];
    const float* g1 = (const float*)d_in[12];
    const float* be1 = (const float*)d_in[13];
    const float* m1 = (const float*)d_in[14];
    const float* v1 = (const float*)d_in[15];
    const float* g2 = (const float*)d_in[16];
    const float* be2 = (const float*)d_in[17];
    const float* m2 = (const float*)d_in[18];
    const float* v2 = (const float*)d_in[19];
    const float* g3 = (const float*)d_in[20];
    const float* be3 = (const float*)d_in[21];
    const float* m3 = (const float*)d_in[22];
    const float* v3 = (const float*)d_in[23];

    float* out = (float*)d_out;

    // Workspace layout (all sections 16B-aligned; packed is 8B-aligned)
    float* ws    = (float*)d_ws;
    float* out2s = ws;                                    // N*128 sliced-16 (L2 out / res / L3 out in-place)
    float* buf2  = out2s + (size_t)N_NODES * 128;         // N*128: agg2 (N*64) then agg3s
    float* agg2  = buf2;                                  // plain [node][64]
    int2*  csr   = (int2*)(buf2 + (size_t)N_NODES * 128); // E int2
    unsigned long long* packed = (unsigned long long*)(csr + N_EDGES); // N ull (8B-aligned)
    int*   seq   = (int*)(packed + N_NODES);              // E
    float* dinv  = (float*)(seq + N_EDGES);               // N
    float* aggx  = dinv + N_NODES;                        // N
    float* kA1   = aggx + N_NODES;                        // 64
    float* kB1   = kA1 + 64;                              // 64
    float* kA2   = kB1 + 64;                              // 128
    float* kB2   = kA2 + 128;                             // 128
    float* kA3   = kB2 + 128;                             // 128
    float* kB3   = kA3 + 128;                             // 128
    int*   offs  = (int*)(kB3 + 128);                     // N+1
    int*   bsum  = offs + N_NODES + 1;                    // SCAN_NB
    int*   bpre  = bsum + SCAN_NB;                        // SCAN_NB

    const int BS = 256;
    auto nb = [](long n) { return (int)((n + 255) / 256); };

    hipMemsetAsync(packed, 0, N_NODES * sizeof(unsigned long long), stream);

    // --- CSR build + degree norm (packed 64-bit atomic, atomic-free fill) ---
    k_degcnt<<<nb(N_EDGES), BS, 0, stream>>>(dst, w, packed, seq, N_EDGES);
    k_scan1<<<SCAN_NB, 256, 0, stream>>>(packed, bsum, N_NODES);
    k_scan2<<<1, 256, 0, stream>>>(bsum, bpre, SCAN_NB);
    k_scan3<<<SCAN_NB, 256, 0, stream>>>(packed, bpre, offs, N_NODES);
    k_dinv<<<nb(N_NODES), BS, 0, stream>>>(packed, dinv, N_NODES);
    k_fill<<<nb(N_EDGES), BS, 0, stream>>>(src, dst, w, dinv, offs, seq, csr, N_EDGES);
    k_bnprep_all<<<1, 320, 0, stream>>>(W1, b1, g1, be1, m1, v1, b2, g2, be2, m2, v2,
                                        b3, g3, be3, m3, v3, kA1, kB1, kA2, kB2, kA3, kB3);

    // --- Layer 1 aggregate (scalar) ---
    k_aggx<<<nb(N_NODES), BS, 0, stream>>>(offs, csr, x, dinv, aggx, N_NODES);

    // --- Layer 2: fused L1-matmul + aggregate (16 thr/node), then 64->128 matmul ---
    k_gather2F<<<nb((long)N_NODES * 16), BS, 0, stream>>>(
        offs, csr, aggx, dinv, kA1, kB1, agg2, N_NODES);
    k_mmT<64, 1, false><<<(N_NODES + 31) / 32, BS, 0, stream>>>(
        agg2, W2, kA2, kB2, nullptr, out2s, N_NODES);

    // --- Layer 3: sliced aggregate (4 thr/node/slice), matmul + relu + res ---
    k_gatherS16<<<8 * ((N_NODES + 63) / 64), BS, 0, stream>>>(
        offs, csr, out2s, dinv, buf2, N_NODES);
    k_mmT<128, 8, true><<<(N_NODES + 31) / 32, BS, 0, stream>>>(
        buf2, W3, kA3, kB3, out2s, out2s, N_NODES);

    // --- per-graph mean pool + final linear (batch sorted, no atomics) ---
    k_poolfinal<<<N_GRAPHS, 128, 0, stream>>>(out2s, batch, Wf, bf, out, N_NODES);
}

// Round 14
// 316.558 us; speedup vs baseline: 1.3345x; 1.0378x over previous
//
#include <hip/hip_runtime.h>

#define N_NODES  50000
#define N_EDGES  640000
#define N_GRAPHS 500
static constexpr float BN_EPS = 1e-5f;
#define SCAN_NB ((N_NODES + 255) / 256)   // 196 blocks
static constexpr float FIX = 16777216.0f;       // 2^24
static constexpr float FIXINV = 5.9604644775390625e-8f;  // 2^-24

// ---------------------------------------------------------------------------
// Packed degree/count: one 64-bit atomic per edge. hi32 = edge count,
// lo32 = weighted degree in 24-bit fixed point. Returned old value gives the
// edge's rank within its dst -> seq[] makes k_fill atomic-free (r13: -50µs).
__global__ void k_degcnt(const int* __restrict__ dst, const float* __restrict__ w,
                         unsigned long long* __restrict__ packed,
                         int* __restrict__ seq, int E) {
    int i = blockIdx.x * blockDim.x + threadIdx.x;
    if (i < E) {
        int d = dst[i];
        unsigned uf = (unsigned)(w[i] * FIX + 0.5f);
        unsigned long long old =
            atomicAdd(&packed[d], (1ULL << 32) | (unsigned long long)uf);
        seq[i] = (int)(old >> 32);
    }
}

__global__ void k_dinv(const unsigned long long* __restrict__ packed,
                       float* __restrict__ dinv, int n) {
    int i = blockIdx.x * blockDim.x + threadIdx.x;
    if (i < n) {
        float wdeg = (float)(unsigned)(packed[i] & 0xFFFFFFFFu) * FIXINV;
        dinv[i] = rsqrtf(wdeg + 1.0f);
    }
}

// --- 3-phase hierarchical exclusive scan of counts (packed hi32) -> offs ---
__global__ void k_scan1(const unsigned long long* __restrict__ packed,
                        int* __restrict__ bsum, int n) {
    __shared__ int red[256];
    int i = blockIdx.x * 256 + threadIdx.x;
    red[threadIdx.x] = (i < n) ? (int)(packed[i] >> 32) : 0;
    __syncthreads();
    for (int off = 128; off > 0; off >>= 1) {
        if (threadIdx.x < off) red[threadIdx.x] += red[threadIdx.x + off];
        __syncthreads();
    }
    if (threadIdx.x == 0) bsum[blockIdx.x] = red[0];
}

__global__ void k_scan2(const int* __restrict__ bsum, int* __restrict__ bpre, int nb) {
    __shared__ int part[256];
    int t = threadIdx.x;
    part[t] = (t < nb) ? bsum[t] : 0;
    __syncthreads();
    for (int off = 1; off < 256; off <<= 1) {
        int v = (t >= off) ? part[t - off] : 0;
        __syncthreads();
        part[t] += v;
        __syncthreads();
    }
    if (t < nb) bpre[t] = (t == 0) ? 0 : part[t - 1];
}

__global__ void k_scan3(const unsigned long long* __restrict__ packed,
                        const int* __restrict__ bpre, int* __restrict__ offs, int n) {
    __shared__ int part[256];
    int i = blockIdx.x * 256 + threadIdx.x;
    int t = threadIdx.x;
    int v = (i < n) ? (int)(packed[i] >> 32) : 0;
    part[t] = v;
    __syncthreads();
    for (int off = 1; off < 256; off <<= 1) {
        int u = (t >= off) ? part[t - off] : 0;
        __syncthreads();
        part[t] += u;
        __syncthreads();
    }
    int excl = bpre[blockIdx.x] + part[t] - v;
    if (i < n) offs[i] = excl;
    if (i == n - 1) offs[n] = N_EDGES;
}

// Atomic-free CSR fill: pos = offs[dst] + seq[e].
__global__ void k_fill(const int* __restrict__ src, const int* __restrict__ dst,
                       const float* __restrict__ w, const float* __restrict__ dinv,
                       const int* __restrict__ offs, const int* __restrict__ seq,
                       int2* __restrict__ csr, int E) {
    int e = blockIdx.x * blockDim.x + threadIdx.x;
    if (e < E) {
        int s = src[e], d = dst[e];
        int pos = offs[d] + seq[e];
        csr[pos] = make_int2(s, __float_as_int(dinv[s] * w[e] * dinv[d]));
    }
}

// Fold bias+BN into per-channel affine. Layer1 additionally folds W1 (rank-1).
__global__ void k_bnprep_all(
    const float* W1,
    const float* b1, const float* g1, const float* be1, const float* m1, const float* v1,
    const float* b2, const float* g2, const float* be2, const float* m2, const float* v2,
    const float* b3, const float* g3, const float* be3, const float* m3, const float* v3,
    float* kA1, float* kB1, float* kA2, float* kB2, float* kA3, float* kB3) {
    int t = threadIdx.x;
    if (t < 64) {
        float s = g1[t] * rsqrtf(v1[t] + BN_EPS);
        kA1[t] = W1[t] * s;
        kB1[t] = (b1[t] - m1[t]) * s + be1[t];
    } else if (t < 192) {
        int c = t - 64;
        float s = g2[c] * rsqrtf(v2[c] + BN_EPS);
        kA2[c] = s; kB2[c] = (b2[c] - m2[c]) * s + be2[c];
    } else if (t < 320) {
        int c = t - 192;
        float s = g3[c] * rsqrtf(v3[c] + BN_EPS);
        kA3[c] = s; kB3[c] = (b3[c] - m3[c]) * s + be3[c];
    }
}

// Layer-1 scalar aggregation over the 200KB x table (4-edge unrolled).
__global__ void k_aggx(const int* __restrict__ offs, const int2* __restrict__ csr,
                       const float* __restrict__ x, const float* __restrict__ dinv,
                       float* __restrict__ aggx, int n) {
    int i = blockIdx.x * blockDim.x + threadIdx.x;
    if (i >= n) return;
    float acc = 0.f;
    int e0 = offs[i], e1 = offs[i + 1];
    int j = e0;
    for (; j + 3 < e1; j += 4) {
        int2 ea = csr[j];
        int2 eb = csr[j + 1];
        int2 ec = csr[j + 2];
        int2 ed = csr[j + 3];
        acc += x[ea.x] * __int_as_float(ea.y) + x[eb.x] * __int_as_float(eb.y)
             + x[ec.x] * __int_as_float(ec.y) + x[ed.x] * __int_as_float(ed.y);
    }
    for (; j < e1; ++j) {
        int2 e = csr[j];
        acc += x[e.x] * __int_as_float(e.y);
    }
    float di = dinv[i];
    aggx[i] = acc + x[i] * di * di;
}

// ---------------------------------------------------------------------------
// Fused layer-1-matmul + layer-2 aggregation. 16 threads/node, 4 ch each.
// 4-edge unroll: 4 independent csr+aggx loads in flight (L2 latency hiding).
__global__ void k_gather2F(const int* __restrict__ offs, const int2* __restrict__ csr,
                           const float* __restrict__ aggx, const float* __restrict__ dinv,
                           const float* __restrict__ kA1, const float* __restrict__ kB1,
                           float* __restrict__ agg2, int n) {
    int gid = blockIdx.x * blockDim.x + threadIdx.x;
    int node = gid >> 4;
    if (node >= n) return;
    int c4 = (gid & 15) * 4;
    float4 wa = *(const float4*)(kA1 + c4);
    float4 wb = *(const float4*)(kB1 + c4);
    float4 acc = {0.f, 0.f, 0.f, 0.f};
    int e0 = offs[node], e1 = offs[node + 1];
    int j = e0;
    for (; j + 3 < e1; j += 4) {
        int2 ea = csr[j];
        int2 eb = csr[j + 1];
        int2 ec = csr[j + 2];
        int2 ed = csr[j + 3];
        float aa = aggx[ea.x];
        float ab = aggx[eb.x];
        float ac = aggx[ec.x];
        float ad = aggx[ed.x];
        float nma = __int_as_float(ea.y);
        float nmb = __int_as_float(eb.y);
        float nmc = __int_as_float(ec.y);
        float nmd = __int_as_float(ed.y);
        acc.x += nma * fmaxf(aa * wa.x + wb.x, 0.f) + nmb * fmaxf(ab * wa.x + wb.x, 0.f)
               + nmc * fmaxf(ac * wa.x + wb.x, 0.f) + nmd * fmaxf(ad * wa.x + wb.x, 0.f);
        acc.y += nma * fmaxf(aa * wa.y + wb.y, 0.f) + nmb * fmaxf(ab * wa.y + wb.y, 0.f)
               + nmc * fmaxf(ac * wa.y + wb.y, 0.f) + nmd * fmaxf(ad * wa.y + wb.y, 0.f);
        acc.z += nma * fmaxf(aa * wa.z + wb.z, 0.f) + nmb * fmaxf(ab * wa.z + wb.z, 0.f)
               + nmc * fmaxf(ac * wa.z + wb.z, 0.f) + nmd * fmaxf(ad * wa.z + wb.z, 0.f);
        acc.w += nma * fmaxf(aa * wa.w + wb.w, 0.f) + nmb * fmaxf(ab * wa.w + wb.w, 0.f)
               + nmc * fmaxf(ac * wa.w + wb.w, 0.f) + nmd * fmaxf(ad * wa.w + wb.w, 0.f);
    }
    for (; j < e1; ++j) {
        int2 e = csr[j];
        float a = aggx[e.x];
        float nm = __int_as_float(e.y);
        acc.x += nm * fmaxf(a * wa.x + wb.x, 0.f);
        acc.y += nm * fmaxf(a * wa.y + wb.y, 0.f);
        acc.z += nm * fmaxf(a * wa.z + wb.z, 0.f);
        acc.w += nm * fmaxf(a * wa.w + wb.w, 0.f);
    }
    float di = dinv[node];
    float d2 = di * di;
    float a = aggx[node];
    acc.x += d2 * fmaxf(a * wa.x + wb.x, 0.f);
    acc.y += d2 * fmaxf(a * wa.y + wb.y, 0.f);
    acc.z += d2 * fmaxf(a * wa.z + wb.z, 0.f);
    acc.w += d2 * fmaxf(a * wa.w + wb.w, 0.f);
    *(float4*)(agg2 + (size_t)node * 64 + c4) = acc;
}

// ---------------------------------------------------------------------------
// Channel-sliced gather (layer 3): slice = blockIdx%8 -> XCD-local 3.2MB table.
// 4 threads/node (coalesced 64B row per edge). 4-edge unroll (4 gathers in
// flight per wave — r13's 2-edge unroll gave 68->54µs; latency still dominant).
__global__ void k_gatherS16(const int* __restrict__ offs, const int2* __restrict__ csr,
                            const float* __restrict__ Hs, const float* __restrict__ dinv,
                            float* __restrict__ aggs, int n) {
    int slice = blockIdx.x & 7;
    int node = (blockIdx.x >> 3) * 64 + threadIdx.x / 4;
    if (node >= n) return;
    int cq = (threadIdx.x % 4) * 4;
    const float* Hb = Hs + (size_t)slice * ((size_t)n * 16);
    float4 acc = {0.f, 0.f, 0.f, 0.f};
    int e0 = offs[node], e1 = offs[node + 1];
    int j = e0;
    for (; j + 3 < e1; j += 4) {
        int2 ea = csr[j];
        int2 eb = csr[j + 1];
        int2 ec = csr[j + 2];
        int2 ed = csr[j + 3];
        float nma = __int_as_float(ea.y);
        float nmb = __int_as_float(eb.y);
        float nmc = __int_as_float(ec.y);
        float nmd = __int_as_float(ed.y);
        float4 ha = *(const float4*)(Hb + (size_t)ea.x * 16 + cq);
        float4 hb = *(const float4*)(Hb + (size_t)eb.x * 16 + cq);
        float4 hc = *(const float4*)(Hb + (size_t)ec.x * 16 + cq);
        float4 hd = *(const float4*)(Hb + (size_t)ed.x * 16 + cq);
        acc.x += ha.x * nma + hb.x * nmb + hc.x * nmc + hd.x * nmd;
        acc.y += ha.y * nma + hb.y * nmb + hc.y * nmc + hd.y * nmd;
        acc.z += ha.z * nma + hb.z * nmb + hc.z * nmc + hd.z * nmd;
        acc.w += ha.w * nma + hb.w * nmb + hc.w * nmc + hd.w * nmd;
    }
    for (; j < e1; ++j) {
        int2 e = csr[j];
        float nm = __int_as_float(e.y);
        float4 hv = *(const float4*)(Hb + (size_t)e.x * 16 + cq);
        acc.x += hv.x * nm;
        acc.y += hv.y * nm;
        acc.z += hv.z * nm;
        acc.w += hv.w * nm;
    }
    float di = dinv[node];
    float d2 = di * di;
    float4 hv = *(const float4*)(Hb + (size_t)node * 16 + cq);
    acc.x += hv.x * d2;
    acc.y += hv.y * d2;
    acc.z += hv.z * d2;
    acc.w += hv.w * d2;
    *(float4*)(aggs + (size_t)slice * ((size_t)n * 16) + (size_t)node * 16 + cq) = acc;
}

// ---------------------------------------------------------------------------
// Register-tiled matmul: 32 nodes/block, x-tile AND W staged in LDS.
// k4/p loops pinned rolled (#pragma unroll 1) — r6/r8 spilled at 256 VGPR when
// the compiler unrolled a load loop. RES=true adds residual and writes
// IN-PLACE (outs may alias res — each slot owned by exactly one thread).
template <int K, int S, bool RES>
__global__ __launch_bounds__(256) void k_mmT(
    const float* __restrict__ Xs, const float* __restrict__ W,
    const float* __restrict__ kA, const float* __restrict__ kB,
    const float* __restrict__ res, float* __restrict__ outs, int n) {
    constexpr int CS = K / S;
    constexpr int KP = K + 4;            // padded LDS row stride (floats)
    constexpr int KH = 64;               // W half-pass rows
    constexpr int NPASS = K / KH;
    __shared__ float xl[32 * KP];
    __shared__ float wl[KH * 128];       // 32 KB
    int base = blockIdx.x * 32;
    int tid = threadIdx.x;
    constexpr int TOT4 = 32 * K / 4;
    constexpr int SL4 = 32 * CS / 4;
    for (int i = tid; i < TOT4; i += 256) {
        int slice = i / SL4;
        int rem = i - slice * SL4;
        int nl = rem / (CS / 4);
        int off4 = (rem % (CS / 4)) * 4;
        int node = base + nl;
        float4 v = {0.f, 0.f, 0.f, 0.f};
        if (node < n)
            v = *(const float4*)(Xs + (size_t)slice * ((size_t)n * CS) + (size_t)node * CS + off4);
        *(float4*)(&xl[nl * KP + slice * CS + off4]) = v;
    }

    int ct = tid & 31;
    int ng = tid >> 5;
    int c4 = ct * 4;
    float4 acc[4];
#pragma unroll
    for (int i = 0; i < 4; ++i) acc[i] = make_float4(0.f, 0.f, 0.f, 0.f);

#pragma unroll 1
    for (int p = 0; p < NPASS; ++p) {
        if (p > 0) __syncthreads();      // WAR on wl
        {
            const float4* Wsrc = (const float4*)(W + (size_t)p * KH * 128);
            float4* wl4 = (float4*)wl;
#pragma unroll 1
            for (int i = tid; i < KH * 32; i += 256) wl4[i] = Wsrc[i];
        }
        __syncthreads();                 // covers xl (p==0) + wl

#pragma unroll 1
        for (int k4 = 0; k4 < KH / 4; ++k4) {
            float4 wv0 = *(const float4*)(&wl[(k4 * 4 + 0) * 128 + c4]);
            float4 wv1 = *(const float4*)(&wl[(k4 * 4 + 1) * 128 + c4]);
            float4 wv2 = *(const float4*)(&wl[(k4 * 4 + 2) * 128 + c4]);
            float4 wv3 = *(const float4*)(&wl[(k4 * 4 + 3) * 128 + c4]);
#pragma unroll
            for (int i = 0; i < 4; ++i) {
                float4 xv = *(const float4*)(&xl[(ng * 4 + i) * KP + p * KH + k4 * 4]);
                acc[i].x += xv.x * wv0.x; acc[i].y += xv.x * wv0.y;
                acc[i].z += xv.x * wv0.z; acc[i].w += xv.x * wv0.w;
                acc[i].x += xv.y * wv1.x; acc[i].y += xv.y * wv1.y;
                acc[i].z += xv.y * wv1.z; acc[i].w += xv.y * wv1.w;
                acc[i].x += xv.z * wv2.x; acc[i].y += xv.z * wv2.y;
                acc[i].z += xv.z * wv2.z; acc[i].w += xv.z * wv2.w;
                acc[i].x += xv.w * wv3.x; acc[i].y += xv.w * wv3.y;
                acc[i].z += xv.w * wv3.z; acc[i].w += xv.w * wv3.w;
            }
        }
    }

    float4 ka = *(const float4*)(kA + c4);
    float4 kb = *(const float4*)(kB + c4);
#pragma unroll
    for (int i = 0; i < 4; ++i) {
        int node = base + ng * 4 + i;
        if (node >= n) continue;
        float4 a = acc[i];
        float4 v;
        v.x = fmaxf(a.x * ka.x + kb.x, 0.f);
        v.y = fmaxf(a.y * ka.y + kb.y, 0.f);
        v.z = fmaxf(a.z * ka.z + kb.z, 0.f);
        v.w = fmaxf(a.w * ka.w + kb.w, 0.f);
        size_t slot = (size_t)(c4 >> 4) * ((size_t)n * 16) + (size_t)node * 16 + (c4 & 15);
        if (RES) {
            float4 rv = *(const float4*)(res + slot);
            v.x += rv.x; v.y += rv.y; v.z += rv.z; v.w += rv.w;
        }
        *(float4*)(outs + slot) = v;
    }
}

// ---------------------------------------------------------------------------
// Per-graph mean-pool + final linear. batch is SORTED: graph g owns a
// contiguous node range found by binary search. No atomics anywhere.
__global__ __launch_bounds__(128) void k_poolfinal(
    const float* __restrict__ Hs, const int* __restrict__ batch,
    const float* __restrict__ Wf, const float* __restrict__ bf,
    float* __restrict__ out, int n) {
    int g = blockIdx.x;
    int t = threadIdx.x;
    int lo = 0, hi = n;
    while (lo < hi) { int m = (lo + hi) >> 1; if (batch[m] < g) lo = m + 1; else hi = m; }
    int start = lo;
    lo = 0; hi = n;
    while (lo < hi) { int m = (lo + hi) >> 1; if (batch[m] < g + 1) lo = m + 1; else hi = m; }
    int end = lo;

    const float* base = Hs + (size_t)(t >> 4) * ((size_t)n * 16) + (t & 15);
    float acc = 0.f;
    for (int i = start; i < end; ++i) acc += base[(size_t)i * 16];
    float v = acc * Wf[t];

    __shared__ float red[128];
    red[t] = v;
    __syncthreads();
    for (int s = 64; s > 0; s >>= 1) {
        if (t < s) red[t] += red[t + s];
        __syncthreads();
    }
    if (t == 0) out[g] = red[0] / fmaxf((float)(end - start), 1.f) + bf[0];
}

// ---------------------------------------------------------------------------
extern "C" void kernel_launch(void* const* d_in, const int* in_sizes, int n_in,
                              void* d_out, int out_size, void* d_ws, size_t ws_size,
                              hipStream_t stream) {
    const float* x     = (const float*)d_in[0];
    const int*   ei    = (const int*)d_in[1];
    const int*   src   = ei;
    const int*   dst   = ei + N_EDGES;
    const float* w     = (const float*)d_in[2];
    const int*   batch = (const int*)d_in[3];
    const float* W1 = (const float*)d_in[4];
    const float* b1 = (const float*)d_in[5];
    const float* W2 = (const float*)d_in[6];
    const float* b2 = (const float*)d_in[7];
    const float* W3 = (const float*)d_in[8];
    const float* b3 = (const float*)d_in[9];
    const float* Wf = (const float*)d_in[10];
    const float* bf = (const float*)d_in[11];
    const float* g1 = (const float*)d_in[12];
    const float* be1 = (const float*)d_in[13];
    const float* m1 = (const float*)d_in[14];
    const float* v1 = (const float*)d_in[15];
    const float* g2 = (const float*)d_in[16];
    const float* be2 = (const float*)d_in[17];
    const float* m2 = (const float*)d_in[18];
    const float* v2 = (const float*)d_in[19];
    const float* g3 = (const float*)d_in[20];
    const float* be3 = (const float*)d_in[21];
    const float* m3 = (const float*)d_in[22];
    const float* v3 = (const float*)d_in[23];

    float* out = (float*)d_out;

    // Workspace layout (all sections 16B-aligned; packed is 8B-aligned)
    float* ws    = (float*)d_ws;
    float* out2s = ws;                                    // N*128 sliced-16 (L2 out / res / L3 out in-place)
    float* buf2  = out2s + (size_t)N_NODES * 128;         // N*128: agg2 (N*64) then agg3s
    float* agg2  = buf2;                                  // plain [node][64]
    int2*  csr   = (int2*)(buf2 + (size_t)N_NODES * 128); // E int2
    unsigned long long* packed = (unsigned long long*)(csr + N_EDGES); // N ull (8B-aligned)
    int*   seq   = (int*)(packed + N_NODES);              // E
    float* dinv  = (float*)(seq + N_EDGES);               // N
    float* aggx  = dinv + N_NODES;                        // N
    float* kA1   = aggx + N_NODES;                        // 64
    float* kB1   = kA1 + 64;                              // 64
    float* kA2   = kB1 + 64;                              // 128
    float* kB2   = kA2 + 128;                             // 128
    float* kA3   = kB2 + 128;                             // 128
    float* kB3   = kA3 + 128;                             // 128
    int*   offs  = (int*)(kB3 + 128);                     // N+1
    int*   bsum  = offs + N_NODES + 1;                    // SCAN_NB
    int*   bpre  = bsum + SCAN_NB;                        // SCAN_NB

    const int BS = 256;
    auto nb = [](long n) { return (int)((n + 255) / 256); };

    hipMemsetAsync(packed, 0, N_NODES * sizeof(unsigned long long), stream);

    // --- CSR build + degree norm (packed 64-bit atomic, atomic-free fill) ---
    k_degcnt<<<nb(N_EDGES), BS, 0, stream>>>(dst, w, packed, seq, N_EDGES);
    k_scan1<<<SCAN_NB, 256, 0, stream>>>(packed, bsum, N_NODES);
    k_scan2<<<1, 256, 0, stream>>>(bsum, bpre, SCAN_NB);
    k_scan3<<<SCAN_NB, 256, 0, stream>>>(packed, bpre, offs, N_NODES);
    k_dinv<<<nb(N_NODES), BS, 0, stream>>>(packed, dinv, N_NODES);
    k_fill<<<nb(N_EDGES), BS, 0, stream>>>(src, dst, w, dinv, offs, seq, csr, N_EDGES);
    k_bnprep_all<<<1, 320, 0, stream>>>(W1, b1, g1, be1, m1, v1, b2, g2, be2, m2, v2,
                                        b3, g3, be3, m3, v3, kA1, kB1, kA2, kB2, kA3, kB3);

    // --- Layer 1 aggregate (scalar) ---
    k_aggx<<<nb(N_NODES), BS, 0, stream>>>(offs, csr, x, dinv, aggx, N_NODES);

    // --- Layer 2: fused L1-matmul + aggregate (16 thr/node), then 64->128 matmul ---
    k_gather2F<<<nb((long)N_NODES * 16), BS, 0, stream>>>(
        offs, csr, aggx, dinv, kA1, kB1, agg2, N_NODES);
    k_mmT<64, 1, false><<<(N_NODES + 31) / 32, BS, 0, stream>>>(
        agg2, W2, kA2, kB2, nullptr, out2s, N_NODES);

    // --- Layer 3: sliced aggregate (4 thr/node/slice), matmul + relu + res ---
    k_gatherS16<<<8 * ((N_NODES + 63) / 64), BS, 0, stream>>>(
        offs, csr, out2s, dinv, buf2, N_NODES);
    k_mmT<128, 8, true><<<(N_NODES + 31) / 32, BS, 0, stream>>>(
        buf2, W3, kA3, kB3, out2s, out2s, N_NODES);

    // --- per-graph mean pool + final linear (batch sorted, no atomics) ---
    k_poolfinal<<<N_GRAPHS, 128, 0, stream>>>(out2s, batch, Wf, bf, out, N_NODES);
}

// Round 15
// 309.520 us; speedup vs baseline: 1.3648x; 1.0227x over previous
//
#include <hip/hip_runtime.h>

#define N_NODES  50000
#define N_EDGES  640000
#define N_GRAPHS 500
static constexpr float BN_EPS = 1e-5f;
#define SCAN_NB ((N_NODES + 255) / 256)   // 196 blocks
static constexpr float FIX = 16777216.0f;       // 2^24
static constexpr float FIXINV = 5.9604644775390625e-8f;  // 2^-24
static constexpr float Q16 = 65535.0f;
static constexpr float Q16INV = 1.0f / 65535.0f;

// csr entry: (src<<16) | round(norm*65535). src<50000<2^16; norm<1 (dinv<=1, w<1).
// Quantization abs err <=7.6e-6/edge (~1e-4 aggregate) << 6.5e-3 threshold.
__device__ __forceinline__ float dec_nm(unsigned e) {
    return (float)(e & 0xFFFFu) * Q16INV;
}

// ---------------------------------------------------------------------------
// Packed degree/count: one 64-bit atomic per edge. hi32 = edge count,
// lo32 = weighted degree in 24-bit fixed point. Returned old value gives the
// edge's rank within its dst -> seq[] makes k_fill atomic-free (r13: -50µs).
__global__ void k_degcnt(const int* __restrict__ dst, const float* __restrict__ w,
                         unsigned long long* __restrict__ packed,
                         int* __restrict__ seq, int E) {
    int i = blockIdx.x * blockDim.x + threadIdx.x;
    if (i < E) {
        int d = dst[i];
        unsigned uf = (unsigned)(w[i] * FIX + 0.5f);
        unsigned long long old =
            atomicAdd(&packed[d], (1ULL << 32) | (unsigned long long)uf);
        seq[i] = (int)(old >> 32);
    }
}

__global__ void k_dinv(const unsigned long long* __restrict__ packed,
                       float* __restrict__ dinv, int n) {
    int i = blockIdx.x * blockDim.x + threadIdx.x;
    if (i < n) {
        float wdeg = (float)(unsigned)(packed[i] & 0xFFFFFFFFu) * FIXINV;
        dinv[i] = rsqrtf(wdeg + 1.0f);
    }
}

// --- 3-phase hierarchical exclusive scan of counts (packed hi32) -> offs ---
__global__ void k_scan1(const unsigned long long* __restrict__ packed,
                        int* __restrict__ bsum, int n) {
    __shared__ int red[256];
    int i = blockIdx.x * 256 + threadIdx.x;
    red[threadIdx.x] = (i < n) ? (int)(packed[i] >> 32) : 0;
    __syncthreads();
    for (int off = 128; off > 0; off >>= 1) {
        if (threadIdx.x < off) red[threadIdx.x] += red[threadIdx.x + off];
        __syncthreads();
    }
    if (threadIdx.x == 0) bsum[blockIdx.x] = red[0];
}

__global__ void k_scan2(const int* __restrict__ bsum, int* __restrict__ bpre, int nb) {
    __shared__ int part[256];
    int t = threadIdx.x;
    part[t] = (t < nb) ? bsum[t] : 0;
    __syncthreads();
    for (int off = 1; off < 256; off <<= 1) {
        int v = (t >= off) ? part[t - off] : 0;
        __syncthreads();
        part[t] += v;
        __syncthreads();
    }
    if (t < nb) bpre[t] = (t == 0) ? 0 : part[t - 1];
}

__global__ void k_scan3(const unsigned long long* __restrict__ packed,
                        const int* __restrict__ bpre, int* __restrict__ offs, int n) {
    __shared__ int part[256];
    int i = blockIdx.x * 256 + threadIdx.x;
    int t = threadIdx.x;
    int v = (i < n) ? (int)(packed[i] >> 32) : 0;
    part[t] = v;
    __syncthreads();
    for (int off = 1; off < 256; off <<= 1) {
        int u = (t >= off) ? part[t - off] : 0;
        __syncthreads();
        part[t] += u;
        __syncthreads();
    }
    int excl = bpre[blockIdx.x] + part[t] - v;
    if (i < n) offs[i] = excl;
    if (i == n - 1) offs[n] = N_EDGES;
}

// Atomic-free CSR fill: pos = offs[dst] + seq[e]. 4-byte packed entry.
__global__ void k_fill(const int* __restrict__ src, const int* __restrict__ dst,
                       const float* __restrict__ w, const float* __restrict__ dinv,
                       const int* __restrict__ offs, const int* __restrict__ seq,
                       unsigned* __restrict__ csr, int E) {
    int e = blockIdx.x * blockDim.x + threadIdx.x;
    if (e < E) {
        int s = src[e], d = dst[e];
        int pos = offs[d] + seq[e];
        float nm = dinv[s] * w[e] * dinv[d];
        unsigned q = (unsigned)(nm * Q16 + 0.5f);
        q = (q > 65535u) ? 65535u : q;
        csr[pos] = ((unsigned)s << 16) | q;
    }
}

// Fold bias+BN into per-channel affine. Layer1 additionally folds W1 (rank-1).
__global__ void k_bnprep_all(
    const float* W1,
    const float* b1, const float* g1, const float* be1, const float* m1, const float* v1,
    const float* b2, const float* g2, const float* be2, const float* m2, const float* v2,
    const float* b3, const float* g3, const float* be3, const float* m3, const float* v3,
    float* kA1, float* kB1, float* kA2, float* kB2, float* kA3, float* kB3) {
    int t = threadIdx.x;
    if (t < 64) {
        float s = g1[t] * rsqrtf(v1[t] + BN_EPS);
        kA1[t] = W1[t] * s;
        kB1[t] = (b1[t] - m1[t]) * s + be1[t];
    } else if (t < 192) {
        int c = t - 64;
        float s = g2[c] * rsqrtf(v2[c] + BN_EPS);
        kA2[c] = s; kB2[c] = (b2[c] - m2[c]) * s + be2[c];
    } else if (t < 320) {
        int c = t - 192;
        float s = g3[c] * rsqrtf(v3[c] + BN_EPS);
        kA3[c] = s; kB3[c] = (b3[c] - m3[c]) * s + be3[c];
    }
}

// Layer-1 scalar aggregation over the 200KB x table (4-edge unrolled).
__global__ void k_aggx(const int* __restrict__ offs, const unsigned* __restrict__ csr,
                       const float* __restrict__ x, const float* __restrict__ dinv,
                       float* __restrict__ aggx, int n) {
    int i = blockIdx.x * blockDim.x + threadIdx.x;
    if (i >= n) return;
    float acc = 0.f;
    int e0 = offs[i], e1 = offs[i + 1];
    int j = e0;
    for (; j + 3 < e1; j += 4) {
        unsigned ea = csr[j];
        unsigned eb = csr[j + 1];
        unsigned ec = csr[j + 2];
        unsigned ed = csr[j + 3];
        acc += x[ea >> 16] * dec_nm(ea) + x[eb >> 16] * dec_nm(eb)
             + x[ec >> 16] * dec_nm(ec) + x[ed >> 16] * dec_nm(ed);
    }
    for (; j < e1; ++j) {
        unsigned e = csr[j];
        acc += x[e >> 16] * dec_nm(e);
    }
    float di = dinv[i];
    aggx[i] = acc + x[i] * di * di;
}

// ---------------------------------------------------------------------------
// Fused layer-1-matmul + layer-2 aggregation. 16 threads/node, 4 ch each.
// 4-edge unroll: 4 independent csr+aggx loads in flight (L2 latency hiding).
__global__ void k_gather2F(const int* __restrict__ offs, const unsigned* __restrict__ csr,
                           const float* __restrict__ aggx, const float* __restrict__ dinv,
                           const float* __restrict__ kA1, const float* __restrict__ kB1,
                           float* __restrict__ agg2, int n) {
    int gid = blockIdx.x * blockDim.x + threadIdx.x;
    int node = gid >> 4;
    if (node >= n) return;
    int c4 = (gid & 15) * 4;
    float4 wa = *(const float4*)(kA1 + c4);
    float4 wb = *(const float4*)(kB1 + c4);
    float4 acc = {0.f, 0.f, 0.f, 0.f};
    int e0 = offs[node], e1 = offs[node + 1];
    int j = e0;
    for (; j + 3 < e1; j += 4) {
        unsigned ea = csr[j];
        unsigned eb = csr[j + 1];
        unsigned ec = csr[j + 2];
        unsigned ed = csr[j + 3];
        float aa = aggx[ea >> 16];
        float ab = aggx[eb >> 16];
        float ac = aggx[ec >> 16];
        float ad = aggx[ed >> 16];
        float nma = dec_nm(ea);
        float nmb = dec_nm(eb);
        float nmc = dec_nm(ec);
        float nmd = dec_nm(ed);
        acc.x += nma * fmaxf(aa * wa.x + wb.x, 0.f) + nmb * fmaxf(ab * wa.x + wb.x, 0.f)
               + nmc * fmaxf(ac * wa.x + wb.x, 0.f) + nmd * fmaxf(ad * wa.x + wb.x, 0.f);
        acc.y += nma * fmaxf(aa * wa.y + wb.y, 0.f) + nmb * fmaxf(ab * wa.y + wb.y, 0.f)
               + nmc * fmaxf(ac * wa.y + wb.y, 0.f) + nmd * fmaxf(ad * wa.y + wb.y, 0.f);
        acc.z += nma * fmaxf(aa * wa.z + wb.z, 0.f) + nmb * fmaxf(ab * wa.z + wb.z, 0.f)
               + nmc * fmaxf(ac * wa.z + wb.z, 0.f) + nmd * fmaxf(ad * wa.z + wb.z, 0.f);
        acc.w += nma * fmaxf(aa * wa.w + wb.w, 0.f) + nmb * fmaxf(ab * wa.w + wb.w, 0.f)
               + nmc * fmaxf(ac * wa.w + wb.w, 0.f) + nmd * fmaxf(ad * wa.w + wb.w, 0.f);
    }
    for (; j < e1; ++j) {
        unsigned e = csr[j];
        float a = aggx[e >> 16];
        float nm = dec_nm(e);
        acc.x += nm * fmaxf(a * wa.x + wb.x, 0.f);
        acc.y += nm * fmaxf(a * wa.y + wb.y, 0.f);
        acc.z += nm * fmaxf(a * wa.z + wb.z, 0.f);
        acc.w += nm * fmaxf(a * wa.w + wb.w, 0.f);
    }
    float di = dinv[node];
    float d2 = di * di;
    float a = aggx[node];
    acc.x += d2 * fmaxf(a * wa.x + wb.x, 0.f);
    acc.y += d2 * fmaxf(a * wa.y + wb.y, 0.f);
    acc.z += d2 * fmaxf(a * wa.z + wb.z, 0.f);
    acc.w += d2 * fmaxf(a * wa.w + wb.w, 0.f);
    *(float4*)(agg2 + (size_t)node * 64 + c4) = acc;
}

// ---------------------------------------------------------------------------
// Channel-sliced gather (layer 3): slice = blockIdx%8 -> XCD-local 3.2MB table.
// 4 threads/node (coalesced 64B row per edge). 4-edge unroll. 4B csr entries
// halve the 8x-replicated csr stream (r14: FETCH 81MB, ~41MB was csr).
__global__ void k_gatherS16(const int* __restrict__ offs, const unsigned* __restrict__ csr,
                            const float* __restrict__ Hs, const float* __restrict__ dinv,
                            float* __restrict__ aggs, int n) {
    int slice = blockIdx.x & 7;
    int node = (blockIdx.x >> 3) * 64 + threadIdx.x / 4;
    if (node >= n) return;
    int cq = (threadIdx.x % 4) * 4;
    const float* Hb = Hs + (size_t)slice * ((size_t)n * 16);
    float4 acc = {0.f, 0.f, 0.f, 0.f};
    int e0 = offs[node], e1 = offs[node + 1];
    int j = e0;
    for (; j + 3 < e1; j += 4) {
        unsigned ea = csr[j];
        unsigned eb = csr[j + 1];
        unsigned ec = csr[j + 2];
        unsigned ed = csr[j + 3];
        float nma = dec_nm(ea);
        float nmb = dec_nm(eb);
        float nmc = dec_nm(ec);
        float nmd = dec_nm(ed);
        float4 ha = *(const float4*)(Hb + (size_t)(ea >> 16) * 16 + cq);
        float4 hb = *(const float4*)(Hb + (size_t)(eb >> 16) * 16 + cq);
        float4 hc = *(const float4*)(Hb + (size_t)(ec >> 16) * 16 + cq);
        float4 hd = *(const float4*)(Hb + (size_t)(ed >> 16) * 16 + cq);
        acc.x += ha.x * nma + hb.x * nmb + hc.x * nmc + hd.x * nmd;
        acc.y += ha.y * nma + hb.y * nmb + hc.y * nmc + hd.y * nmd;
        acc.z += ha.z * nma + hb.z * nmb + hc.z * nmc + hd.z * nmd;
        acc.w += ha.w * nma + hb.w * nmb + hc.w * nmc + hd.w * nmd;
    }
    for (; j < e1; ++j) {
        unsigned e = csr[j];
        float nm = dec_nm(e);
        float4 hv = *(const float4*)(Hb + (size_t)(e >> 16) * 16 + cq);
        acc.x += hv.x * nm;
        acc.y += hv.y * nm;
        acc.z += hv.z * nm;
        acc.w += hv.w * nm;
    }
    float di = dinv[node];
    float d2 = di * di;
    float4 hv = *(const float4*)(Hb + (size_t)node * 16 + cq);
    acc.x += hv.x * d2;
    acc.y += hv.y * d2;
    acc.z += hv.z * d2;
    acc.w += hv.w * d2;
    *(float4*)(aggs + (size_t)slice * ((size_t)n * 16) + (size_t)node * 16 + cq) = acc;
}

// ---------------------------------------------------------------------------
// Register-tiled matmul: 32 nodes/block, x-tile AND W staged in LDS.
// k4/p loops pinned rolled (#pragma unroll 1) — r6/r8 spilled at 256 VGPR when
// the compiler unrolled a load loop. RES=true adds residual and writes
// IN-PLACE (outs may alias res — each slot owned by exactly one thread).
template <int K, int S, bool RES>
__global__ __launch_bounds__(256) void k_mmT(
    const float* __restrict__ Xs, const float* __restrict__ W,
    const float* __restrict__ kA, const float* __restrict__ kB,
    const float* __restrict__ res, float* __restrict__ outs, int n) {
    constexpr int CS = K / S;
    constexpr int KP = K + 4;            // padded LDS row stride (floats)
    constexpr int KH = 64;               // W half-pass rows
    constexpr int NPASS = K / KH;
    __shared__ float xl[32 * KP];
    __shared__ float wl[KH * 128];       // 32 KB
    int base = blockIdx.x * 32;
    int tid = threadIdx.x;
    constexpr int TOT4 = 32 * K / 4;
    constexpr int SL4 = 32 * CS / 4;
    for (int i = tid; i < TOT4; i += 256) {
        int slice = i / SL4;
        int rem = i - slice * SL4;
        int nl = rem / (CS / 4);
        int off4 = (rem % (CS / 4)) * 4;
        int node = base + nl;
        float4 v = {0.f, 0.f, 0.f, 0.f};
        if (node < n)
            v = *(const float4*)(Xs + (size_t)slice * ((size_t)n * CS) + (size_t)node * CS + off4);
        *(float4*)(&xl[nl * KP + slice * CS + off4]) = v;
    }

    int ct = tid & 31;
    int ng = tid >> 5;
    int c4 = ct * 4;
    float4 acc[4];
#pragma unroll
    for (int i = 0; i < 4; ++i) acc[i] = make_float4(0.f, 0.f, 0.f, 0.f);

#pragma unroll 1
    for (int p = 0; p < NPASS; ++p) {
        if (p > 0) __syncthreads();      // WAR on wl
        {
            const float4* Wsrc = (const float4*)(W + (size_t)p * KH * 128);
            float4* wl4 = (float4*)wl;
#pragma unroll 1
            for (int i = tid; i < KH * 32; i += 256) wl4[i] = Wsrc[i];
        }
        __syncthreads();                 // covers xl (p==0) + wl

#pragma unroll 1
        for (int k4 = 0; k4 < KH / 4; ++k4) {
            float4 wv0 = *(const float4*)(&wl[(k4 * 4 + 0) * 128 + c4]);
            float4 wv1 = *(const float4*)(&wl[(k4 * 4 + 1) * 128 + c4]);
            float4 wv2 = *(const float4*)(&wl[(k4 * 4 + 2) * 128 + c4]);
            float4 wv3 = *(const float4*)(&wl[(k4 * 4 + 3) * 128 + c4]);
#pragma unroll
            for (int i = 0; i < 4; ++i) {
                float4 xv = *(const float4*)(&xl[(ng * 4 + i) * KP + p * KH + k4 * 4]);
                acc[i].x += xv.x * wv0.x; acc[i].y += xv.x * wv0.y;
                acc[i].z += xv.x * wv0.z; acc[i].w += xv.x * wv0.w;
                acc[i].x += xv.y * wv1.x; acc[i].y += xv.y * wv1.y;
                acc[i].z += xv.y * wv1.z; acc[i].w += xv.y * wv1.w;
                acc[i].x += xv.z * wv2.x; acc[i].y += xv.z * wv2.y;
                acc[i].z += xv.z * wv2.z; acc[i].w += xv.z * wv2.w;
                acc[i].x += xv.w * wv3.x; acc[i].y += xv.w * wv3.y;
                acc[i].z += xv.w * wv3.z; acc[i].w += xv.w * wv3.w;
            }
        }
    }

    float4 ka = *(const float4*)(kA + c4);
    float4 kb = *(const float4*)(kB + c4);
#pragma unroll
    for (int i = 0; i < 4; ++i) {
        int node = base + ng * 4 + i;
        if (node >= n) continue;
        float4 a = acc[i];
        float4 v;
        v.x = fmaxf(a.x * ka.x + kb.x, 0.f);
        v.y = fmaxf(a.y * ka.y + kb.y, 0.f);
        v.z = fmaxf(a.z * ka.z + kb.z, 0.f);
        v.w = fmaxf(a.w * ka.w + kb.w, 0.f);
        size_t slot = (size_t)(c4 >> 4) * ((size_t)n * 16) + (size_t)node * 16 + (c4 & 15);
        if (RES) {
            float4 rv = *(const float4*)(res + slot);
            v.x += rv.x; v.y += rv.y; v.z += rv.z; v.w += rv.w;
        }
        *(float4*)(outs + slot) = v;
    }
}

// ---------------------------------------------------------------------------
// Per-graph mean-pool + final linear. batch is SORTED: graph g owns a
// contiguous node range found by binary search. No atomics anywhere.
__global__ __launch_bounds__(128) void k_poolfinal(
    const float* __restrict__ Hs, const int* __restrict__ batch,
    const float* __restrict__ Wf, const float* __restrict__ bf,
    float* __restrict__ out, int n) {
    int g = blockIdx.x;
    int t = threadIdx.x;
    int lo = 0, hi = n;
    while (lo < hi) { int m = (lo + hi) >> 1; if (batch[m] < g) lo = m + 1; else hi = m; }
    int start = lo;
    lo = 0; hi = n;
    while (lo < hi) { int m = (lo + hi) >> 1; if (batch[m] < g + 1) lo = m + 1; else hi = m; }
    int end = lo;

    const float* base = Hs + (size_t)(t >> 4) * ((size_t)n * 16) + (t & 15);
    float acc = 0.f;
    for (int i = start; i < end; ++i) acc += base[(size_t)i * 16];
    float v = acc * Wf[t];

    __shared__ float red[128];
    red[t] = v;
    __syncthreads();
    for (int s = 64; s > 0; s >>= 1) {
        if (t < s) red[t] += red[t + s];
        __syncthreads();
    }
    if (t == 0) out[g] = red[0] / fmaxf((float)(end - start), 1.f) + bf[0];
}

// ---------------------------------------------------------------------------
extern "C" void kernel_launch(void* const* d_in, const int* in_sizes, int n_in,
                              void* d_out, int out_size, void* d_ws, size_t ws_size,
                              hipStream_t stream) {
    const float* x     = (const float*)d_in[0];
    const int*   ei    = (const int*)d_in[1];
    const int*   src   = ei;
    const int*   dst   = ei + N_EDGES;
    const float* w     = (const float*)d_in[2];
    const int*   batch = (const int*)d_in[3];
    const float* W1 = (const float*)d_in[4];
    const float* b1 = (const float*)d_in[5];
    const float* W2 = (const float*)d_in[6];
    const float* b2 = (const float*)d_in[7];
    const float* W3 = (const float*)d_in[8];
    const float* b3 = (const float*)d_in[9];
    const float* Wf = (const float*)d_in[10];
    const float* bf = (const float*)d_in[11];
    const float* g1 = (const float*)d_in[12];
    const float* be1 = (const float*)d_in[13];
    const float* m1 = (const float*)d_in[14];
    const float* v1 = (const float*)d_in[15];
    const float* g2 = (const float*)d_in[16];
    const float* be2 = (const float*)d_in[17];
    const float* m2 = (const float*)d_in[18];
    const float* v2 = (const float*)d_in[19];
    const float* g3 = (const float*)d_in[20];
    const float* be3 = (const float*)d_in[21];
    const float* m3 = (const float*)d_in[22];
    const float* v3 = (const float*)d_in[23];

    float* out = (float*)d_out;

    // Workspace layout (all sections 16B-aligned; packed is 8B-aligned)
    float* ws    = (float*)d_ws;
    float* out2s = ws;                                    // N*128 sliced-16 (L2 out / res / L3 out in-place)
    float* buf2  = out2s + (size_t)N_NODES * 128;         // N*128: agg2 (N*64) then agg3s
    float* agg2  = buf2;                                  // plain [node][64]
    unsigned* csr = (unsigned*)(buf2 + (size_t)N_NODES * 128); // E uint (4B packed)
    unsigned long long* packed = (unsigned long long*)(csr + N_EDGES); // N ull
    int*   seq   = (int*)(packed + N_NODES);              // E
    float* dinv  = (float*)(seq + N_EDGES);               // N
    float* aggx  = dinv + N_NODES;                        // N
    float* kA1   = aggx + N_NODES;                        // 64
    float* kB1   = kA1 + 64;                              // 64
    float* kA2   = kB1 + 64;                              // 128
    float* kB2   = kA2 + 128;                             // 128
    float* kA3   = kB2 + 128;                             // 128
    float* kB3   = kA3 + 128;                             // 128
    int*   offs  = (int*)(kB3 + 128);                     // N+1
    int*   bsum  = offs + N_NODES + 1;                    // SCAN_NB
    int*   bpre  = bsum + SCAN_NB;                        // SCAN_NB

    const int BS = 256;
    auto nb = [](long n) { return (int)((n + 255) / 256); };

    hipMemsetAsync(packed, 0, N_NODES * sizeof(unsigned long long), stream);

    // --- CSR build + degree norm (packed 64-bit atomic, atomic-free fill) ---
    k_degcnt<<<nb(N_EDGES), BS, 0, stream>>>(dst, w, packed, seq, N_EDGES);
    k_scan1<<<SCAN_NB, 256, 0, stream>>>(packed, bsum, N_NODES);
    k_scan2<<<1, 256, 0, stream>>>(bsum, bpre, SCAN_NB);
    k_scan3<<<SCAN_NB, 256, 0, stream>>>(packed, bpre, offs, N_NODES);
    k_dinv<<<nb(N_NODES), BS, 0, stream>>>(packed, dinv, N_NODES);
    k_fill<<<nb(N_EDGES), BS, 0, stream>>>(src, dst, w, dinv, offs, seq, csr, N_EDGES);
    k_bnprep_all<<<1, 320, 0, stream>>>(W1, b1, g1, be1, m1, v1, b2, g2, be2, m2, v2,
                                        b3, g3, be3, m3, v3, kA1, kB1, kA2, kB2, kA3, kB3);

    // --- Layer 1 aggregate (scalar) ---
    k_aggx<<<nb(N_NODES), BS, 0, stream>>>(offs, csr, x, dinv, aggx, N_NODES);

    // --- Layer 2: fused L1-matmul + aggregate (16 thr/node), then 64->128 matmul ---
    k_gather2F<<<nb((long)N_NODES * 16), BS, 0, stream>>>(
        offs, csr, aggx, dinv, kA1, kB1, agg2, N_NODES);
    k_mmT<64, 1, false><<<(N_NODES + 31) / 32, BS, 0, stream>>>(
        agg2, W2, kA2, kB2, nullptr, out2s, N_NODES);

    // --- Layer 3: sliced aggregate (4 thr/node/slice), matmul + relu + res ---
    k_gatherS16<<<8 * ((N_NODES + 63) / 64), BS, 0, stream>>>(
        offs, csr, out2s, dinv, buf2, N_NODES);
    k_mmT<128, 8, true><<<(N_NODES + 31) / 32, BS, 0, stream>>>(
        buf2, W3, kA3, kB3, out2s, out2s, N_NODES);

    // --- per-graph mean pool + final linear (batch sorted, no atomics) ---
    k_poolfinal<<<N_GRAPHS, 128, 0, stream>>>(out2s, batch, Wf, bf, out, N_NODES);
}